// Round 1
// baseline (771.578 us; speedup 1.0000x reference)
//
#include <hip/hip_runtime.h>

// FFB encoder fused kernel, MI355X (gfx950).
// Design notes:
//  - All 5 hidden layers + heads fused in one kernel; x lives in LDS per 32-row tile.
//  - bf16 MFMA (16x16x32) with hi/lo split, 3 products: x_hi*W_hi + x_lo*W_hi + x_hi*W_lo.
//    Combined quantization ~2^-17 rel -> output error ~1e-3 (threshold 1e-1).
//  - Weights pre-packed (per call, ws re-poisoned) to B-fragment layout:
//    [l][kb][n][40] bf16 (32 k-values + 8 pad shorts => 80B rows, 16B-aligned frags).
//  - sin via v_sin_f32 (input in revolutions, explicit fract reduction).
//  - LDS x planes: stride 264 shorts (528B = 132 dw, 4-bank rotation/row -> 2-way max).
//    x_lo plane base offset +16 shorts (8 dword banks) so packed epilogue writes
//    (even lanes -> hi plane, odd lanes -> lo plane) hit disjoint bank halves.

#define TM 32
#define XSTRIDE 264
#define XOFF (TM*XSTRIDE + 16)          // shorts; +32B => +8 bank shift for lo plane
#define K5 0.79577471545947667f         // 5/(2*pi)

typedef __attribute__((ext_vector_type(8))) short v8s;
typedef __attribute__((ext_vector_type(4))) float v4f;

#define MFMA16(a, b, c) __builtin_amdgcn_mfma_f32_16x16x32_bf16(a, b, c, 0, 0, 0)

__device__ __forceinline__ float sin_rev(float u) {
    // sin(2*pi*u); v_sin_f32 takes revolutions, reduce first.
    u = u - floorf(u);
    return __builtin_amdgcn_sinf(u);
}

__device__ __forceinline__ void split_bf16(float x, unsigned short& h, unsigned short& l) {
    unsigned int u = __float_as_uint(x);
    unsigned int r = u + 0x7fffu + ((u >> 16) & 1u);   // RNE to bf16
    h = (unsigned short)(r >> 16);
    float hf = __uint_as_float(((unsigned int)h) << 16);
    float d = x - hf;                                   // exact
    unsigned int u2 = __float_as_uint(d);
    unsigned int r2 = u2 + 0x7fffu + ((u2 >> 16) & 1u);
    l = (unsigned short)(r2 >> 16);
}

// ---------------- weight packing ----------------
// Wh  [5][256][256] -> planes [5][8][256][40]  (409600 shorts each)
// Whh [5][256][64]  -> planes [5][8][64][40]   (102400 shorts each)
__global__ __launch_bounds__(256) void ffb_pack(
    const float* __restrict__ Wh, const float* __restrict__ Whh,
    short* __restrict__ wh_hi, short* __restrict__ wh_lo,
    short* __restrict__ whh_hi, short* __restrict__ whh_lo)
{
    int j = blockIdx.x * 256 + threadIdx.x;
    if (j < 409600) {
        int kk = j % 40;
        int rest = j / 40;
        int n = rest & 255;
        int kbl = rest >> 8;               // l*8 + kb
        unsigned short h = 0, lo = 0;
        if (kk < 32) {
            int k = (kbl & 7) * 32 + kk;
            int l = kbl >> 3;
            split_bf16(Wh[(l * 256 + k) * 256 + n], h, lo);
        }
        wh_hi[j] = (short)h; wh_lo[j] = (short)lo;
    } else {
        int j2 = j - 409600;
        if (j2 < 102400) {
            int kk = j2 % 40;
            int rest = j2 / 40;
            int n = rest & 63;
            int kbl = rest >> 6;
            unsigned short h = 0, lo = 0;
            if (kk < 32) {
                int k = (kbl & 7) * 32 + kk;
                int l = kbl >> 3;
                split_bf16(Whh[(l * 256 + k) * 64 + n], h, lo);
            }
            whh_hi[j2] = (short)h; whh_lo[j2] = (short)lo;
        }
    }
}

// ---------------- main fused kernel ----------------
__global__ __launch_bounds__(256, 4) void ffb_main(
    const float* __restrict__ pos, const float* __restrict__ gfeat,
    const float* __restrict__ ffnA, const float* __restrict__ W0,
    const float* __restrict__ b0, const float* __restrict__ bh,
    const float* __restrict__ bhh,
    const short* __restrict__ wh_hi, const short* __restrict__ wh_lo,
    const short* __restrict__ whh_hi, const short* __restrict__ whh_lo,
    float* __restrict__ out)
{
    __shared__ __align__(16) short s_x[2 * TM * XSTRIDE + 16];  // hi @0, lo @XOFF
    __shared__ __align__(16) float s_g[TM * 44];                // grid feats, padded
    __shared__ float s_pos[TM * 3];

    const int tid = threadIdx.x;
    const int row0 = blockIdx.x * TM;
    const int lane = tid & 63;
    const int w = tid >> 6;        // wave 0..3
    const int q = lane >> 4;       // quad
    const int i = lane & 15;
    const int m0 = (w & 1) * 16;   // m-tile rows [m0, m0+16)
    const int nh = w >> 1;         // n-half for GEMM1 cols, n-half for head cols

    // stage pos + grid feats
    if (tid < TM * 3) s_pos[tid] = pos[row0 * 3 + tid];
    for (int k2 = tid; k2 < TM * 40; k2 += 256)
        s_g[(k2 / 40) * 44 + (k2 % 40)] = gfeat[row0 * 40 + k2];
    __syncthreads();

    // layer 0: x = sin(5*(pos@W0 + b0))
    {
        const int c = tid;
        const float w00 = W0[c], w01 = W0[256 + c], w02 = W0[512 + c], bc = b0[c];
        #pragma unroll 4
        for (int r = 0; r < TM; r++) {
            float d = s_pos[r * 3 + 0] * w00 + s_pos[r * 3 + 1] * w01
                    + s_pos[r * 3 + 2] * w02 + bc;
            float v = sin_rev(d * K5);
            unsigned short h, lo; split_bf16(v, h, lo);
            s_x[r * XSTRIDE + c] = (short)h;
            s_x[XOFF + r * XSTRIDE + c] = (short)lo;
        }
    }
    __syncthreads();

    float cout[2][4];
    #pragma unroll
    for (int t = 0; t < 2; t++)
        #pragma unroll
        for (int r = 0; r < 4; r++) cout[t][r] = 0.f;

    const int aoff = (m0 + i) * XSTRIDE + q * 8;         // + kb*32 (shorts)
    const int woff = (nh * 128 + i) * 40 + q * 8;        // GEMM1 B frag base
    const int w2off = (nh * 32 + i) * 40 + q * 8;        // GEMM2 B frag base

    for (int l = 0; l < 5; l++) {
        // ---- GEMM1: C1 = x @ Wh[l]  (wave: 16 rows x 128 cols) ----
        v4f C1[8];
        #pragma unroll
        for (int t = 0; t < 8; t++) C1[t] = (v4f){0.f, 0.f, 0.f, 0.f};

        const short* bbh = wh_hi + l * 81920 + woff;
        const short* bbl = wh_lo + l * 81920 + woff;
        #pragma unroll
        for (int kb = 0; kb < 8; kb++) {
            v8s ah = *(const v8s*)&s_x[aoff + kb * 32];
            v8s al = *(const v8s*)&s_x[XOFF + aoff + kb * 32];
            const short* ph = bbh + kb * 10240;
            const short* pl = bbl + kb * 10240;
            #pragma unroll
            for (int t = 0; t < 8; t++) {
                v8s bh_f = *(const v8s*)(ph + t * 640);
                v8s bl_f = *(const v8s*)(pl + t * 640);
                C1[t] = MFMA16(ah, bh_f, C1[t]);
                C1[t] = MFMA16(al, bh_f, C1[t]);
                C1[t] = MFMA16(ah, bl_f, C1[t]);
            }
        }
        __syncthreads();   // all waves done reading x_l before overwrite

        // ---- epilogue: x = sin(5*(C1+bh)) + sin(2pi*sigma*(g@ffnA)) ----
        const float sig = (float)(1 << l);
        #pragma unroll
        for (int t = 0; t < 8; t++) {
            const int col = nh * 128 + t * 16 + i;
            const float bias = bh[l * 256 + col];
            float af[8];
            #pragma unroll
            for (int f = 0; f < 8; f++) af[f] = ffnA[(l * 8 + f) * 256 + col];
            #pragma unroll
            for (int r = 0; r < 4; r++) {
                const int row = m0 + q * 4 + r;
                float gd = 0.f;
                #pragma unroll
                for (int f = 0; f < 8; f++) gd += s_g[row * 44 + l * 8 + f] * af[f];
                float v = sin_rev((C1[t][r] + bias) * K5) + sin_rev(sig * gd);
                unsigned short h, lo; split_bf16(v, h, lo);
                unsigned int pk = (unsigned int)h | ((unsigned int)lo << 16);
                unsigned int ppk = (unsigned int)__shfl_xor((int)pk, 1, 64);
                // even lane writes hi-plane dword (cols 2c,2c+1); odd writes lo-plane
                unsigned int dw = (lane & 1) ? ((ppk >> 16) | (pk & 0xffff0000u))
                                             : ((pk & 0xffffu) | (ppk << 16));
                int idx = row * XSTRIDE + ((lane & 1) ? (XOFF + col - 1) : col);
                *(unsigned int*)&s_x[idx] = dw;
            }
        }
        __syncthreads();   // new x visible

        // ---- GEMM2: head, C2 = x_new @ Wh_high[l] (wave: 16 rows x 32 cols) ----
        v4f C2[2];
        C2[0] = (v4f){0.f, 0.f, 0.f, 0.f};
        C2[1] = (v4f){0.f, 0.f, 0.f, 0.f};
        const short* b2h = whh_hi + l * 20480 + w2off;
        const short* b2l = whh_lo + l * 20480 + w2off;
        #pragma unroll
        for (int kb = 0; kb < 8; kb++) {
            v8s ah = *(const v8s*)&s_x[aoff + kb * 32];
            v8s al = *(const v8s*)&s_x[XOFF + aoff + kb * 32];
            const short* ph = b2h + kb * 2560;
            const short* pl = b2l + kb * 2560;
            #pragma unroll
            for (int t = 0; t < 2; t++) {
                v8s bh_f = *(const v8s*)(ph + t * 640);
                v8s bl_f = *(const v8s*)(pl + t * 640);
                C2[t] = MFMA16(ah, bh_f, C2[t]);
                C2[t] = MFMA16(al, bh_f, C2[t]);
                C2[t] = MFMA16(ah, bl_f, C2[t]);
            }
        }
        #pragma unroll
        for (int t = 0; t < 2; t++) {
            const int col2 = nh * 32 + t * 16 + i;
            const float b2 = bhh[l * 64 + col2];
            #pragma unroll
            for (int r = 0; r < 4; r++)
                cout[t][r] += sin_rev((C2[t][r] + b2) * K5);
        }
        // no barrier needed: next GEMM1 reads same x; writes only after its barrier
    }

    // ---- store x_out ----
    #pragma unroll
    for (int t = 0; t < 2; t++) {
        const int col2 = nh * 32 + t * 16 + i;
        #pragma unroll
        for (int r = 0; r < 4; r++)
            out[(row0 + m0 + q * 4 + r) * 64 + col2] = cout[t][r];
    }
}

extern "C" void kernel_launch(void* const* d_in, const int* in_sizes, int n_in,
                              void* d_out, int out_size, void* d_ws, size_t ws_size,
                              hipStream_t stream) {
    const float* pos   = (const float*)d_in[0];
    const float* gfeat = (const float*)d_in[1];
    const float* ffnA  = (const float*)d_in[2];
    const float* W0    = (const float*)d_in[3];
    const float* b0    = (const float*)d_in[4];
    const float* Wh    = (const float*)d_in[5];
    const float* bh    = (const float*)d_in[6];
    const float* Whh   = (const float*)d_in[7];
    const float* bhh   = (const float*)d_in[8];
    float* out = (float*)d_out;
    const int N = in_sizes[0] / 3;

    // ws layout (shorts): wh_hi 409600 | wh_lo 409600 | whh_hi 102400 | whh_lo 102400
    short* wh_hi  = (short*)d_ws;
    short* wh_lo  = wh_hi + 409600;
    short* whh_hi = wh_lo + 409600;
    short* whh_lo = whh_hi + 102400;

    ffb_pack<<<2000, 256, 0, stream>>>(Wh, Whh, wh_hi, wh_lo, whh_hi, whh_lo);
    ffb_main<<<N / TM, 256, 0, stream>>>(pos, gfeat, ffnA, W0, b0, bh, bhh,
                                         wh_hi, wh_lo, whh_hi, whh_lo, out);
}

// Round 2
// 481.987 us; speedup vs baseline: 1.6008x; 1.6008x over previous
//
#include <hip/hip_runtime.h>

// FFB encoder fused kernel, MI355X (gfx950). Round 2.
//  - GEMM1 (256x256) now uses mfma_f32_32x32x16_bf16: 2x MACs per B-byte vs
//    16x16x32, and each wave owns a UNIQUE 64-col slice (no B duplication).
//  - GEMM2 (256x64 head) stays 16x16x32 but each wave owns a unique 16-col
//    slice (was 2x duplicated). Total B L2 traffic ~13.1 GB -> ~6.55 GB.
//  - Dense B-fragment packing: each fragment is 64 lanes x 16 B contiguous
//    (1 KB), loaded as global_load_dwordx4 at base + lane*16 -> no pad bytes,
//    no 64B-line amplification.
//  - Register double-buffer: B frags for kb+1 issued before MFMA on kb.
//  - hi/lo bf16 split, 3 products (x_hi*W_hi + x_lo*W_hi + x_hi*W_lo).
//  - x lives in LDS (stride 264 shorts, lo plane at +16 shorts), shfl-packed
//    dword writes in epilogue (same scheme as round 1; conflicts measured ~0).

#define TM 32
#define XSTRIDE 264
#define XOFF (TM*XSTRIDE + 16)
#define K5 0.79577471545947667f         // 5/(2*pi)

typedef __attribute__((ext_vector_type(8))) short v8s;
typedef __attribute__((ext_vector_type(4))) float v4f;
typedef __attribute__((ext_vector_type(16))) float v16f;

#define MFMA16(a, b, c) __builtin_amdgcn_mfma_f32_16x16x32_bf16(a, b, c, 0, 0, 0)
#define MFMA32(a, b, c) __builtin_amdgcn_mfma_f32_32x32x16_bf16(a, b, c, 0, 0, 0)

__device__ __forceinline__ float sin_rev(float u) {
    u = u - floorf(u);
    return __builtin_amdgcn_sinf(u);
}

__device__ __forceinline__ void split_bf16(float x, unsigned short& h, unsigned short& l) {
    unsigned int u = __float_as_uint(x);
    unsigned int r = u + 0x7fffu + ((u >> 16) & 1u);   // RNE to bf16
    h = (unsigned short)(r >> 16);
    float hf = __uint_as_float(((unsigned int)h) << 16);
    float d = x - hf;                                   // exact
    unsigned int u2 = __float_as_uint(d);
    unsigned int r2 = u2 + 0x7fffu + ((u2 >> 16) & 1u);
    l = (unsigned short)(r2 >> 16);
}

// ---------------- weight packing (dense fragment layout) ----------------
// GEMM1 planes: [l][kb16][nt8][lane64][8]  (327680 shorts/plane)
//   n = nt*32 + (lane&31); k = kb*16 + (lane>>5)*8 + jj
// GEMM2 planes: [l][kb8][nt4][lane64][8]   (81920 shorts/plane)
//   n = nt*16 + (lane&15); k = kb*32 + (lane>>4)*8 + jj
__global__ __launch_bounds__(256) void ffb_pack(
    const float* __restrict__ Wh, const float* __restrict__ Whh,
    short* __restrict__ wh_hi, short* __restrict__ wh_lo,
    short* __restrict__ whh_hi, short* __restrict__ whh_lo)
{
    int j = blockIdx.x * 256 + threadIdx.x;
    if (j < 327680) {                      // 5*256*256, coalesced read over n
        int n = j & 255, k = (j >> 8) & 255, l = j >> 16;
        unsigned short h, lo;
        split_bf16(Wh[j], h, lo);          // j == (l*256+k)*256+n
        int nt = n >> 5, lane = (n & 31) | (((k >> 3) & 1) << 5);
        int kb = k >> 4, jj = k & 7;
        int dst = ((l * 16 + kb) * 8 + nt) * 512 + lane * 8 + jj;
        wh_hi[dst] = (short)h; wh_lo[dst] = (short)lo;
    } else {
        int j2 = j - 327680;
        if (j2 < 81920) {                  // 5*256*64
            int n = j2 & 63, k = (j2 >> 6) & 255, l = j2 >> 14;
            unsigned short h, lo;
            split_bf16(Whh[j2], h, lo);
            int nt = n >> 4, lane = (n & 15) | (((k >> 3) & 3) << 4);
            int kb = k >> 5, jj = k & 7;
            int dst = ((l * 8 + kb) * 4 + nt) * 512 + lane * 8 + jj;
            whh_hi[dst] = (short)h; whh_lo[dst] = (short)lo;
        }
    }
}

// ---------------- main fused kernel ----------------
__global__ __launch_bounds__(256, 4) void ffb_main(
    const float* __restrict__ pos, const float* __restrict__ gfeat,
    const float* __restrict__ ffnA, const float* __restrict__ W0,
    const float* __restrict__ b0, const float* __restrict__ bh,
    const float* __restrict__ bhh,
    const short* __restrict__ wh_hi, const short* __restrict__ wh_lo,
    const short* __restrict__ whh_hi, const short* __restrict__ whh_lo,
    float* __restrict__ out)
{
    __shared__ __align__(16) short s_x[2 * TM * XSTRIDE + 16];  // hi @0, lo @XOFF
    __shared__ __align__(16) float s_g[TM * 44];
    __shared__ float s_pos[TM * 3];

    const int tid = threadIdx.x;
    const int row0 = blockIdx.x * TM;
    const int lane = tid & 63;
    const int w = tid >> 6;        // wave 0..3
    const int i = lane & 15;
    const int q = lane >> 4;
    const int m32 = lane & 31;     // row within 32x32 m-tile
    const int h = lane >> 5;       // k-half for 32x32 frags

    if (tid < TM * 3) s_pos[tid] = pos[row0 * 3 + tid];
    for (int k2 = tid; k2 < TM * 40; k2 += 256)
        s_g[(k2 / 40) * 44 + (k2 % 40)] = gfeat[row0 * 40 + k2];
    __syncthreads();

    // layer 0: x = sin(5*(pos@W0 + b0))
    {
        const int c = tid;
        const float w00 = W0[c], w01 = W0[256 + c], w02 = W0[512 + c], bc = b0[c];
        #pragma unroll 4
        for (int r = 0; r < TM; r++) {
            float d = s_pos[r * 3 + 0] * w00 + s_pos[r * 3 + 1] * w01
                    + s_pos[r * 3 + 2] * w02 + bc;
            float v = sin_rev(d * K5);
            unsigned short hh, ll; split_bf16(v, hh, ll);
            s_x[r * XSTRIDE + c] = (short)hh;
            s_x[XOFF + r * XSTRIDE + c] = (short)ll;
        }
    }
    __syncthreads();

    float cout[2][4];
    #pragma unroll
    for (int m = 0; m < 2; m++)
        #pragma unroll
        for (int r = 0; r < 4; r++) cout[m][r] = 0.f;

    // A-frag LDS offsets
    const int a1off = m32 * XSTRIDE + h * 8;               // + kb*16 (GEMM1)
    const int a2off0 = i * XSTRIDE + q * 8;                // m-tile 0, + kb*32 (GEMM2)
    const int a2off1 = (16 + i) * XSTRIDE + q * 8;         // m-tile 1

    for (int l = 0; l < 5; l++) {
        // ---- GEMM1: 32 rows x 64 cols per wave, 32x32x16 MFMA ----
        v16f C1[2];
        #pragma unroll
        for (int t = 0; t < 2; t++)
            #pragma unroll
            for (int r = 0; r < 16; r++) C1[t][r] = 0.f;

        {
            const short* bh0 = wh_hi + l * 65536 + (2 * w) * 512 + lane * 8;
            const short* bl0 = wh_lo + l * 65536 + (2 * w) * 512 + lane * 8;
            v8s bc0h = *(const v8s*)(bh0);
            v8s bc1h = *(const v8s*)(bh0 + 512);
            v8s bc0l = *(const v8s*)(bl0);
            v8s bc1l = *(const v8s*)(bl0 + 512);
            #pragma unroll
            for (int kb = 0; kb < 16; kb++) {
                const int kn = (kb < 15) ? (kb + 1) : 15;
                v8s bn0h = *(const v8s*)(bh0 + kn * 4096);
                v8s bn1h = *(const v8s*)(bh0 + kn * 4096 + 512);
                v8s bn0l = *(const v8s*)(bl0 + kn * 4096);
                v8s bn1l = *(const v8s*)(bl0 + kn * 4096 + 512);
                v8s ah = *(const v8s*)&s_x[a1off + kb * 16];
                v8s al = *(const v8s*)&s_x[XOFF + a1off + kb * 16];
                C1[0] = MFMA32(ah, bc0h, C1[0]);
                C1[0] = MFMA32(al, bc0h, C1[0]);
                C1[0] = MFMA32(ah, bc0l, C1[0]);
                C1[1] = MFMA32(ah, bc1h, C1[1]);
                C1[1] = MFMA32(al, bc1h, C1[1]);
                C1[1] = MFMA32(ah, bc1l, C1[1]);
                bc0h = bn0h; bc1h = bn1h; bc0l = bn0l; bc1l = bn1l;
            }
        }
        __syncthreads();   // all waves done reading x_l

        // ---- epilogue: x = sin(5*(C1+bh)) + sin(2pi*sigma*(g@ffnA)) ----
        const float sig = (float)(1 << l);
        float af[2][8], bias[2];
        #pragma unroll
        for (int t = 0; t < 2; t++) {
            const int col = w * 64 + t * 32 + m32;
            bias[t] = bh[l * 256 + col];
            #pragma unroll
            for (int f = 0; f < 8; f++) af[t][f] = ffnA[(l * 8 + f) * 256 + col];
        }
        #pragma unroll
        for (int r = 0; r < 16; r++) {
            const int row = (r & 3) + 8 * (r >> 2) + 4 * h;
            const float* gr = &s_g[row * 44 + l * 8];
            float g0 = gr[0], g1 = gr[1], g2 = gr[2], g3 = gr[3];
            float g4 = gr[4], g5 = gr[5], g6 = gr[6], g7 = gr[7];
            #pragma unroll
            for (int t = 0; t < 2; t++) {
                float gd = g0 * af[t][0] + g1 * af[t][1] + g2 * af[t][2] + g3 * af[t][3]
                         + g4 * af[t][4] + g5 * af[t][5] + g6 * af[t][6] + g7 * af[t][7];
                float v = sin_rev((C1[t][r] + bias[t]) * K5) + sin_rev(sig * gd);
                unsigned short hh, ll; split_bf16(v, hh, ll);
                unsigned int pk = (unsigned int)hh | ((unsigned int)ll << 16);
                unsigned int ppk = (unsigned int)__shfl_xor((int)pk, 1, 64);
                unsigned int dw = (lane & 1) ? ((ppk >> 16) | (pk & 0xffff0000u))
                                             : ((pk & 0xffffu) | (ppk << 16));
                const int col = w * 64 + t * 32 + m32;
                int idx = row * XSTRIDE + ((lane & 1) ? (XOFF + col - 1) : col);
                *(unsigned int*)&s_x[idx] = dw;
            }
        }
        __syncthreads();   // new x visible

        // ---- GEMM2: head, 32 rows x 16 cols per wave, 16x16x32 MFMA ----
        v4f C2[2];
        C2[0] = (v4f){0.f, 0.f, 0.f, 0.f};
        C2[1] = (v4f){0.f, 0.f, 0.f, 0.f};
        {
            const short* bh0 = whh_hi + l * 16384 + w * 512 + lane * 8;
            const short* bl0 = whh_lo + l * 16384 + w * 512 + lane * 8;
            v8s bch = *(const v8s*)(bh0);
            v8s bcl = *(const v8s*)(bl0);
            #pragma unroll
            for (int kb = 0; kb < 8; kb++) {
                const int kn = (kb < 7) ? (kb + 1) : 7;
                v8s bnh = *(const v8s*)(bh0 + kn * 2048);
                v8s bnl = *(const v8s*)(bl0 + kn * 2048);
                v8s a0h = *(const v8s*)&s_x[a2off0 + kb * 32];
                v8s a0l = *(const v8s*)&s_x[XOFF + a2off0 + kb * 32];
                v8s a1h = *(const v8s*)&s_x[a2off1 + kb * 32];
                v8s a1l = *(const v8s*)&s_x[XOFF + a2off1 + kb * 32];
                C2[0] = MFMA16(a0h, bch, C2[0]);
                C2[0] = MFMA16(a0l, bch, C2[0]);
                C2[0] = MFMA16(a0h, bcl, C2[0]);
                C2[1] = MFMA16(a1h, bch, C2[1]);
                C2[1] = MFMA16(a1l, bch, C2[1]);
                C2[1] = MFMA16(a1h, bcl, C2[1]);
                bch = bnh; bcl = bnl;
            }
        }
        const float b2 = bhh[l * 64 + w * 16 + i];
        #pragma unroll
        for (int m = 0; m < 2; m++)
            #pragma unroll
            for (int r = 0; r < 4; r++)
                cout[m][r] += sin_rev((C2[m][r] + b2) * K5);
        // no barrier: next GEMM1 reads same x; overwrites happen after its barrier
    }

    // ---- store x_out ----
    #pragma unroll
    for (int m = 0; m < 2; m++)
        #pragma unroll
        for (int r = 0; r < 4; r++)
            out[(row0 + m * 16 + q * 4 + r) * 64 + w * 16 + i] = cout[m][r];
}

extern "C" void kernel_launch(void* const* d_in, const int* in_sizes, int n_in,
                              void* d_out, int out_size, void* d_ws, size_t ws_size,
                              hipStream_t stream) {
    const float* pos   = (const float*)d_in[0];
    const float* gfeat = (const float*)d_in[1];
    const float* ffnA  = (const float*)d_in[2];
    const float* W0    = (const float*)d_in[3];
    const float* b0    = (const float*)d_in[4];
    const float* Wh    = (const float*)d_in[5];
    const float* bh    = (const float*)d_in[6];
    const float* Whh   = (const float*)d_in[7];
    const float* bhh   = (const float*)d_in[8];
    float* out = (float*)d_out;
    const int N = in_sizes[0] / 3;

    // ws layout (shorts): wh_hi 327680 | wh_lo 327680 | whh_hi 81920 | whh_lo 81920
    short* wh_hi  = (short*)d_ws;
    short* wh_lo  = wh_hi + 327680;
    short* whh_hi = wh_lo + 327680;
    short* whh_lo = whh_hi + 81920;

    ffb_pack<<<1600, 256, 0, stream>>>(Wh, Whh, wh_hi, wh_lo, whh_hi, whh_lo);
    ffb_main<<<N / TM, 256, 0, stream>>>(pos, gfeat, ffnA, W0, b0, bh, bhh,
                                         wh_hi, wh_lo, whh_hi, whh_lo, out);
}

// Round 3
// 445.669 us; speedup vs baseline: 1.7313x; 1.0815x over previous
//
#include <hip/hip_runtime.h>

// FFB encoder fused kernel, MI355X (gfx950). Round 3.
//  vs round 2:
//  - Grid branch (g @ ffnA*sigma) computed by MFMA instead of per-output VALU
//    FMAs: ffnA pre-scaled by 2^l (exact) and packed as 32x32x16 B-frags with
//    the two k-halves duplicated; g packed as hi/lo bf16 A-frag (k0-7=g_hi,
//    k8-15=g_lo) -> (g_hi+g_lo)*a in one MFMA per n-tile per layer.
//  - Head GEMM uses 2 products (x_hi*W_hi + x_lo*W_hi): head feeds output
//    directly (no chain amplification), so W_lo is dropped -> half B traffic.
//  - C1/C2 accumulators initialized with bias (removes epilogue adds).
//  - Same LDS x scheme as round 2 (verified): stride 264, lo plane at +XOFF,
//    shfl-packed dword epilogue writes. LDS total 40352 B -> 4 blocks/CU.

#define TM 32
#define XSTRIDE 264
#define XOFF (TM*XSTRIDE + 16)
#define GSTRIDE 48                      // shorts; 96 B rows, 16B-aligned
#define K5 0.79577471545947667f         // 5/(2*pi)

typedef __attribute__((ext_vector_type(8))) short v8s;
typedef __attribute__((ext_vector_type(4))) float v4f;
typedef __attribute__((ext_vector_type(16))) float v16f;

#define MFMA16(a, b, c) __builtin_amdgcn_mfma_f32_16x16x32_bf16(a, b, c, 0, 0, 0)
#define MFMA32(a, b, c) __builtin_amdgcn_mfma_f32_32x32x16_bf16(a, b, c, 0, 0, 0)

__device__ __forceinline__ float sin_rev(float u) {
    u = u - floorf(u);
    return __builtin_amdgcn_sinf(u);
}

__device__ __forceinline__ void split_bf16(float x, unsigned short& h, unsigned short& l) {
    unsigned int u = __float_as_uint(x);
    unsigned int r = u + 0x7fffu + ((u >> 16) & 1u);   // RNE to bf16
    h = (unsigned short)(r >> 16);
    float hf = __uint_as_float(((unsigned int)h) << 16);
    float d = x - hf;                                   // exact
    unsigned int u2 = __float_as_uint(d);
    unsigned int r2 = u2 + 0x7fffu + ((u2 >> 16) & 1u);
    l = (unsigned short)(r2 >> 16);
}

// ---------------- weight packing ----------------
// GEMM1 planes: [l][kb16][nt8][lane64][8]  (327680 shorts/plane)
// GEMM2 hi:     [l][kb8][nt4][lane64][8]   (81920 shorts)
// G-frags:      [l][nt8][lane64][8]        (20480 shorts) = ffnA[l][jj][n]*2^l
//               (both k-halves duplicated)
__global__ __launch_bounds__(256) void ffb_pack(
    const float* __restrict__ Wh, const float* __restrict__ Whh,
    const float* __restrict__ ffnA,
    short* __restrict__ wh_hi, short* __restrict__ wh_lo,
    short* __restrict__ whh_hi, short* __restrict__ gfrag)
{
    int j = blockIdx.x * 256 + threadIdx.x;
    if (j < 327680) {                      // 5*256*256, coalesced over n
        int n = j & 255, k = (j >> 8) & 255, l = j >> 16;
        unsigned short h, lo;
        split_bf16(Wh[j], h, lo);
        int nt = n >> 5, lane = (n & 31) | (((k >> 3) & 1) << 5);
        int kb = k >> 4, jj = k & 7;
        int dst = ((l * 16 + kb) * 8 + nt) * 512 + lane * 8 + jj;
        wh_hi[dst] = (short)h; wh_lo[dst] = (short)lo;
    } else if (j < 409600) {               // 5*256*64
        int j2 = j - 327680;
        int n = j2 & 63, k = (j2 >> 6) & 255, l = j2 >> 14;
        unsigned short h, lo;
        split_bf16(Whh[j2], h, lo);
        int nt = n >> 4, lane = (n & 15) | (((k >> 3) & 3) << 4);
        int kb = k >> 5, jj = k & 7;
        int dst = ((l * 8 + kb) * 4 + nt) * 512 + lane * 8 + jj;
        whh_hi[dst] = (short)h;
    } else {                               // 5*8*64*8 G-frags
        int j3 = j - 409600;
        if (j3 < 20480) {
            int jj = j3 & 7, lane = (j3 >> 3) & 63, nt = (j3 >> 9) & 7, l = j3 >> 12;
            int n = nt * 32 + (lane & 31);
            float v = ffnA[(l * 8 + jj) * 256 + n] * (float)(1 << l);
            unsigned short h, lo;
            split_bf16(v, h, lo);
            gfrag[j3] = (short)h;          // same value for both k-halves
        }
    }
}

// ---------------- main fused kernel ----------------
__global__ __launch_bounds__(256, 4) void ffb_main(
    const float* __restrict__ pos, const float* __restrict__ gfeat,
    const float* __restrict__ W0, const float* __restrict__ b0,
    const float* __restrict__ bh, const float* __restrict__ bhh,
    const short* __restrict__ wh_hi, const short* __restrict__ wh_lo,
    const short* __restrict__ whh_hi, const short* __restrict__ gfrag,
    float* __restrict__ out)
{
    __shared__ __align__(16) short s_x[2 * TM * XSTRIDE + 16];  // hi @0, lo @XOFF
    __shared__ __align__(16) short s_gh[TM * GSTRIDE];          // g hi bf16
    __shared__ __align__(16) short s_gl[TM * GSTRIDE];          // g lo bf16
    __shared__ float s_pos[TM * 3];

    const int tid = threadIdx.x;
    const int row0 = blockIdx.x * TM;
    const int lane = tid & 63;
    const int w = tid >> 6;        // wave 0..3
    const int i = lane & 15;
    const int q = lane >> 4;
    const int m32 = lane & 31;
    const int h = lane >> 5;       // k-half for 32x32 frags

    if (tid < TM * 3) s_pos[tid] = pos[row0 * 3 + tid];
    for (int k2 = tid; k2 < TM * 40; k2 += 256) {
        int r = k2 / 40, f = k2 % 40;
        unsigned short hh, ll; split_bf16(gfeat[row0 * 40 + k2], hh, ll);
        s_gh[r * GSTRIDE + f] = (short)hh;
        s_gl[r * GSTRIDE + f] = (short)ll;
    }
    __syncthreads();

    // layer 0: x = sin(5*(pos@W0 + b0))
    {
        const int c = tid;
        const float w00 = W0[c], w01 = W0[256 + c], w02 = W0[512 + c], bc = b0[c];
        #pragma unroll 4
        for (int r = 0; r < TM; r++) {
            float d = s_pos[r * 3 + 0] * w00 + s_pos[r * 3 + 1] * w01
                    + s_pos[r * 3 + 2] * w02 + bc;
            float v = sin_rev(d * K5);
            unsigned short hh, ll; split_bf16(v, hh, ll);
            s_x[r * XSTRIDE + c] = (short)hh;
            s_x[XOFF + r * XSTRIDE + c] = (short)ll;
        }
    }
    __syncthreads();

    float cout[2][4];
    #pragma unroll
    for (int m = 0; m < 2; m++)
        #pragma unroll
        for (int r = 0; r < 4; r++) cout[m][r] = 0.f;

    const int a1off = m32 * XSTRIDE + h * 8;               // + kb*16 (GEMM1)
    const int a2off0 = i * XSTRIDE + q * 8;                // + kb*32 (GEMM2)
    const int a2off1 = (16 + i) * XSTRIDE + q * 8;

    for (int l = 0; l < 5; l++) {
        // ---- bias-init C1, prefetch G B-frags ----
        const float bias0 = bh[l * 256 + w * 64 + m32];
        const float bias1 = bh[l * 256 + w * 64 + 32 + m32];
        v16f C1[2];
        #pragma unroll
        for (int r = 0; r < 16; r++) { C1[0][r] = bias0; C1[1][r] = bias1; }
        v8s gb0 = *(const v8s*)(gfrag + ((l * 8 + w * 2 + 0) * 64 + lane) * 8);
        v8s gb1 = *(const v8s*)(gfrag + ((l * 8 + w * 2 + 1) * 64 + lane) * 8);

        // ---- GEMM1: 32 rows x 64 cols per wave, 32x32x16 MFMA ----
        {
            const short* bh0 = wh_hi + l * 65536 + (2 * w) * 512 + lane * 8;
            const short* bl0 = wh_lo + l * 65536 + (2 * w) * 512 + lane * 8;
            v8s bc0h = *(const v8s*)(bh0);
            v8s bc1h = *(const v8s*)(bh0 + 512);
            v8s bc0l = *(const v8s*)(bl0);
            v8s bc1l = *(const v8s*)(bl0 + 512);
            #pragma unroll
            for (int kb = 0; kb < 16; kb++) {
                const int kn = (kb < 15) ? (kb + 1) : 15;
                v8s bn0h = *(const v8s*)(bh0 + kn * 4096);
                v8s bn1h = *(const v8s*)(bh0 + kn * 4096 + 512);
                v8s bn0l = *(const v8s*)(bl0 + kn * 4096);
                v8s bn1l = *(const v8s*)(bl0 + kn * 4096 + 512);
                v8s ah = *(const v8s*)&s_x[a1off + kb * 16];
                v8s al = *(const v8s*)&s_x[XOFF + a1off + kb * 16];
                C1[0] = MFMA32(ah, bc0h, C1[0]);
                C1[0] = MFMA32(al, bc0h, C1[0]);
                C1[0] = MFMA32(ah, bc0l, C1[0]);
                C1[1] = MFMA32(ah, bc1h, C1[1]);
                C1[1] = MFMA32(al, bc1h, C1[1]);
                C1[1] = MFMA32(ah, bc1l, C1[1]);
                bc0h = bn0h; bc1h = bn1h; bc0l = bn0l; bc1l = bn1l;
            }
        }
        __syncthreads();   // all waves done reading x_l

        // ---- epilogue: x = sin(5*(C1)) + sin(2pi*G), G = g@(ffnA*2^l) ----
        const short* gp = (lane < 32) ? s_gh : s_gl;   // h=0: g_hi, h=1: g_lo
        v8s ga = *(const v8s*)&gp[m32 * GSTRIDE + l * 8];
        #pragma unroll
        for (int t = 0; t < 2; t++) {
            v16f Z = {};
            v16f G = MFMA32(ga, (t ? gb1 : gb0), Z);
            const int col = w * 64 + t * 32 + m32;
            #pragma unroll
            for (int r = 0; r < 16; r++) {
                const int row = (r & 3) + 8 * (r >> 2) + 4 * h;
                float v = sin_rev(C1[t][r] * K5) + sin_rev(G[r]);
                unsigned short hh, ll; split_bf16(v, hh, ll);
                unsigned int pk = (unsigned int)hh | ((unsigned int)ll << 16);
                unsigned int ppk = (unsigned int)__shfl_xor((int)pk, 1, 64);
                unsigned int dw = (lane & 1) ? ((ppk >> 16) | (pk & 0xffff0000u))
                                             : ((pk & 0xffffu) | (ppk << 16));
                int idx = row * XSTRIDE + ((lane & 1) ? (XOFF + col - 1) : col);
                *(unsigned int*)&s_x[idx] = dw;
            }
        }
        __syncthreads();   // new x visible

        // ---- GEMM2: head, 2-product, 32 rows x 16 cols per wave ----
        const float b2 = bhh[l * 64 + w * 16 + i];
        v4f C2[2];
        C2[0] = (v4f){b2, b2, b2, b2};
        C2[1] = (v4f){b2, b2, b2, b2};
        {
            const short* bp = whh_hi + l * 16384 + w * 512 + lane * 8;
            v8s bch = *(const v8s*)(bp);
            #pragma unroll
            for (int kb = 0; kb < 8; kb++) {
                const int kn = (kb < 7) ? (kb + 1) : 7;
                v8s bnh = *(const v8s*)(bp + kn * 2048);
                v8s a0h = *(const v8s*)&s_x[a2off0 + kb * 32];
                v8s a0l = *(const v8s*)&s_x[XOFF + a2off0 + kb * 32];
                v8s a1h = *(const v8s*)&s_x[a2off1 + kb * 32];
                v8s a1l = *(const v8s*)&s_x[XOFF + a2off1 + kb * 32];
                C2[0] = MFMA16(a0h, bch, C2[0]);
                C2[0] = MFMA16(a0l, bch, C2[0]);
                C2[1] = MFMA16(a1h, bch, C2[1]);
                C2[1] = MFMA16(a1l, bch, C2[1]);
                bch = bnh;
            }
        }
        #pragma unroll
        for (int m = 0; m < 2; m++)
            #pragma unroll
            for (int r = 0; r < 4; r++)
                cout[m][r] += sin_rev(C2[m][r] * K5);
        // no barrier: next GEMM1 reads same x; overwrites after its own barrier
    }

    // ---- store x_out ----
    #pragma unroll
    for (int m = 0; m < 2; m++)
        #pragma unroll
        for (int r = 0; r < 4; r++)
            out[(row0 + m * 16 + q * 4 + r) * 64 + w * 16 + i] = cout[m][r];
}

extern "C" void kernel_launch(void* const* d_in, const int* in_sizes, int n_in,
                              void* d_out, int out_size, void* d_ws, size_t ws_size,
                              hipStream_t stream) {
    const float* pos   = (const float*)d_in[0];
    const float* gfeat = (const float*)d_in[1];
    const float* ffnA  = (const float*)d_in[2];
    const float* W0    = (const float*)d_in[3];
    const float* b0    = (const float*)d_in[4];
    const float* Wh    = (const float*)d_in[5];
    const float* bh    = (const float*)d_in[6];
    const float* Whh   = (const float*)d_in[7];
    const float* bhh   = (const float*)d_in[8];
    float* out = (float*)d_out;
    const int N = in_sizes[0] / 3;

    // ws (shorts): wh_hi 327680 | wh_lo 327680 | whh_hi 81920 | gfrag 20480
    short* wh_hi  = (short*)d_ws;
    short* wh_lo  = wh_hi + 327680;
    short* whh_hi = wh_lo + 327680;
    short* gfrag  = whh_hi + 81920;

    ffb_pack<<<1680, 256, 0, stream>>>(Wh, Whh, ffnA, wh_hi, wh_lo, whh_hi, gfrag);
    ffb_main<<<N / TM, 256, 0, stream>>>(pos, gfeat, W0, b0, bh, bhh,
                                         wh_hi, wh_lo, whh_hi, gfrag, out);
}

// Round 4
// 430.225 us; speedup vs baseline: 1.7934x; 1.0359x over previous
//
#include <hip/hip_runtime.h>

// FFB encoder fused kernel, MI355X (gfx950). Round 4.
//  vs round 3:
//  - PRECISION RESTORED (R3 absmax 0.0989 was 1 ulp from the 0.1 threshold):
//    grid branch gets an ffnA-lo plane (+1 MFMA32 per n-tile), head gets its
//    W_lo product back (3-product). Target absmax ~0.035.
//  - Pack kernel rewritten: 1 thread per 8-short fragment row, coalesced
//    dwordx4 stores (R3 did 2B stores at 16B stride into poisoned ws ->
//    ~70us of the bench gap).
//  - VALU trims in main: Wh/Whh/bh/bhh pre-scaled by K5 (no per-output mul),
//    truncation hi-split (lo still RNE; dropped term is 2^-17 level),
//    v_fract for sin range reduction, v_perm_b32 single-instr hi/lo blend.
//  - Structure (TM=32, stride-264 LDS x planes, shfl-packed dword epilogue
//    writes, 32x32x16 GEMM1 / 16x16x32 head, reg double-buffered B) proven
//    in R2/R3 -> unchanged.

#define TM 32
#define XSTRIDE 264
#define XOFF (TM*XSTRIDE + 16)
#define GSTRIDE 48
#define K5 0.79577471545947667f         // 5/(2*pi)

typedef __attribute__((ext_vector_type(8))) short v8s;
typedef __attribute__((ext_vector_type(4))) float v4f;
typedef __attribute__((ext_vector_type(16))) float v16f;

#define MFMA16(a, b, c) __builtin_amdgcn_mfma_f32_16x16x32_bf16(a, b, c, 0, 0, 0)
#define MFMA32(a, b, c) __builtin_amdgcn_mfma_f32_32x32x16_bf16(a, b, c, 0, 0, 0)

__device__ __forceinline__ float sin_rev(float u) {
#if __has_builtin(__builtin_amdgcn_fractf)
    return __builtin_amdgcn_sinf(__builtin_amdgcn_fractf(u));
#else
    return __builtin_amdgcn_sinf(u - floorf(u));
#endif
}

// RNE hi/lo split (used in pack + staging, off critical path)
__device__ __forceinline__ void split_bf16(float x, unsigned short& h, unsigned short& l) {
    unsigned int u = __float_as_uint(x);
    unsigned int r = u + 0x7fffu + ((u >> 16) & 1u);
    h = (unsigned short)(r >> 16);
    float hf = __uint_as_float(((unsigned int)h) << 16);
    float d = x - hf;
    unsigned int u2 = __float_as_uint(d);
    unsigned int r2 = u2 + 0x7fffu + ((u2 >> 16) & 1u);
    l = (unsigned short)(r2 >> 16);
}

// trunc hi + RNE lo, packed: bits0-15 = hi, bits16-31 = lo (main-loop hot path)
__device__ __forceinline__ unsigned int split_pack(float x) {
    unsigned int u = __float_as_uint(x);
    float hf = __uint_as_float(u & 0xffff0000u);
    float d = x - hf;                                   // exact
    unsigned int u2 = __float_as_uint(d);
    unsigned int r2 = u2 + 0x7fffu + ((u2 >> 16) & 1u);
    return (u >> 16) | (r2 & 0xffff0000u);
}

// ---------------- weight packing ----------------
// wh planes:  [l][kb16][nt8][lane64][8]  (327680 shorts each), scaled by K5
// whh planes: [l][kb8][nt4][lane64][8]   (81920 shorts each),  scaled by K5
// gf planes:  [l][nt8][lane64][8]        (20480 shorts each),  ffnA*2^l,
//             both k-halves duplicated (value depends on lane&31 only)
__global__ __launch_bounds__(256) void ffb_pack(
    const float* __restrict__ Wh, const float* __restrict__ Whh,
    const float* __restrict__ ffnA,
    short* __restrict__ wh_hi, short* __restrict__ wh_lo,
    short* __restrict__ whh_hi, short* __restrict__ whh_lo,
    short* __restrict__ gf_hi, short* __restrict__ gf_lo)
{
    int t = blockIdx.x * 256 + threadIdx.x;
    if (t < 40960) {                       // (l, kb, nt, lane)
        int lane = t & 63, nt = (t >> 6) & 7, kb = (t >> 9) & 15, l = t >> 13;
        int n = nt * 32 + (lane & 31);
        int k0 = kb * 16 + (lane >> 5) * 8;
        short hs[8], ls[8];
        #pragma unroll
        for (int jj = 0; jj < 8; jj++) {
            unsigned short h, lo;
            split_bf16(Wh[(l * 256 + k0 + jj) * 256 + n] * K5, h, lo);
            hs[jj] = (short)h; ls[jj] = (short)lo;
        }
        *(v8s*)(wh_hi + t * 8) = *(v8s*)hs;     // dst == t*8 by construction
        *(v8s*)(wh_lo + t * 8) = *(v8s*)ls;
    } else if (t < 51200) {
        int t2 = t - 40960;                // (l, kb, nt, lane)
        int lane = t2 & 63, nt = (t2 >> 6) & 3, kb = (t2 >> 8) & 7, l = t2 >> 11;
        int n = nt * 16 + (lane & 15);
        int k0 = kb * 32 + (lane >> 4) * 8;
        short hs[8], ls[8];
        #pragma unroll
        for (int jj = 0; jj < 8; jj++) {
            unsigned short h, lo;
            split_bf16(Whh[(l * 256 + k0 + jj) * 64 + n] * K5, h, lo);
            hs[jj] = (short)h; ls[jj] = (short)lo;
        }
        *(v8s*)(whh_hi + t2 * 8) = *(v8s*)hs;
        *(v8s*)(whh_lo + t2 * 8) = *(v8s*)ls;
    } else if (t < 53760) {
        int t3 = t - 51200;                // (l, nt, lane)
        int lane = t3 & 63, nt = (t3 >> 6) & 7, l = t3 >> 9;
        int n = nt * 32 + (lane & 31);
        short hs[8], ls[8];
        #pragma unroll
        for (int jj = 0; jj < 8; jj++) {
            unsigned short h, lo;
            split_bf16(ffnA[(l * 8 + jj) * 256 + n] * (float)(1 << l), h, lo);
            hs[jj] = (short)h; ls[jj] = (short)lo;
        }
        *(v8s*)(gf_hi + t3 * 8) = *(v8s*)hs;
        *(v8s*)(gf_lo + t3 * 8) = *(v8s*)ls;
    }
}

// ---------------- main fused kernel ----------------
__global__ __launch_bounds__(256, 4) void ffb_main(
    const float* __restrict__ pos, const float* __restrict__ gfeat,
    const float* __restrict__ W0, const float* __restrict__ b0,
    const float* __restrict__ bh, const float* __restrict__ bhh,
    const short* __restrict__ wh_hi, const short* __restrict__ wh_lo,
    const short* __restrict__ whh_hi, const short* __restrict__ whh_lo,
    const short* __restrict__ gf_hi, const short* __restrict__ gf_lo,
    float* __restrict__ out)
{
    __shared__ __align__(16) short s_x[2 * TM * XSTRIDE + 16];  // hi @0, lo @XOFF
    __shared__ __align__(16) short s_gh[TM * GSTRIDE];
    __shared__ __align__(16) short s_gl[TM * GSTRIDE];
    __shared__ float s_pos[TM * 3];

    const int tid = threadIdx.x;
    const int row0 = blockIdx.x * TM;
    const int lane = tid & 63;
    const int w = tid >> 6;
    const int i = lane & 15;
    const int q = lane >> 4;
    const int m32 = lane & 31;
    const int h = lane >> 5;

    const unsigned int psel = (lane & 1) ? 0x03020706u : 0x05040100u;
    const int pbase = (lane & 1) ? (XOFF - 1) : 0;

    if (tid < TM * 3) s_pos[tid] = pos[row0 * 3 + tid];
    for (int k2 = tid; k2 < TM * 40; k2 += 256) {
        int r = k2 / 40, f = k2 % 40;
        unsigned short hh, ll; split_bf16(gfeat[row0 * 40 + k2], hh, ll);
        s_gh[r * GSTRIDE + f] = (short)hh;
        s_gl[r * GSTRIDE + f] = (short)ll;
    }
    __syncthreads();

    // layer 0: x = sin(5*(pos@W0 + b0))
    {
        const int c = tid;
        const float w00 = W0[c], w01 = W0[256 + c], w02 = W0[512 + c], bc = b0[c];
        #pragma unroll 4
        for (int r = 0; r < TM; r++) {
            float d = s_pos[r * 3 + 0] * w00 + s_pos[r * 3 + 1] * w01
                    + s_pos[r * 3 + 2] * w02 + bc;
            unsigned int dw = split_pack(sin_rev(d * K5));
            s_x[r * XSTRIDE + c] = (short)(dw & 0xffffu);
            s_x[XOFF + r * XSTRIDE + c] = (short)(dw >> 16);
        }
    }
    __syncthreads();

    float cout[2][4];
    #pragma unroll
    for (int m = 0; m < 2; m++)
        #pragma unroll
        for (int r = 0; r < 4; r++) cout[m][r] = 0.f;

    const int a1off = m32 * XSTRIDE + h * 8;               // + kb*16 (GEMM1)
    const int a2off0 = i * XSTRIDE + q * 8;                // + kb*32 (GEMM2)
    const int a2off1 = (16 + i) * XSTRIDE + q * 8;

    for (int l = 0; l < 5; l++) {
        // ---- bias-init C1 (biases pre-scaled by K5), prefetch G B-frags ----
        const float bias0 = bh[l * 256 + w * 64 + m32] * K5;
        const float bias1 = bh[l * 256 + w * 64 + 32 + m32] * K5;
        v16f C1[2];
        #pragma unroll
        for (int r = 0; r < 16; r++) { C1[0][r] = bias0; C1[1][r] = bias1; }
        v8s gb0h = *(const v8s*)(gf_hi + ((l * 8 + w * 2 + 0) * 64 + lane) * 8);
        v8s gb1h = *(const v8s*)(gf_hi + ((l * 8 + w * 2 + 1) * 64 + lane) * 8);
        v8s gb0l = *(const v8s*)(gf_lo + ((l * 8 + w * 2 + 0) * 64 + lane) * 8);
        v8s gb1l = *(const v8s*)(gf_lo + ((l * 8 + w * 2 + 1) * 64 + lane) * 8);

        // ---- GEMM1: 32 rows x 64 cols per wave, 32x32x16, 3 products ----
        {
            const short* bh0 = wh_hi + l * 65536 + (2 * w) * 512 + lane * 8;
            const short* bl0 = wh_lo + l * 65536 + (2 * w) * 512 + lane * 8;
            v8s bc0h = *(const v8s*)(bh0);
            v8s bc1h = *(const v8s*)(bh0 + 512);
            v8s bc0l = *(const v8s*)(bl0);
            v8s bc1l = *(const v8s*)(bl0 + 512);
            #pragma unroll
            for (int kb = 0; kb < 16; kb++) {
                const int kn = (kb < 15) ? (kb + 1) : 15;
                v8s bn0h = *(const v8s*)(bh0 + kn * 4096);
                v8s bn1h = *(const v8s*)(bh0 + kn * 4096 + 512);
                v8s bn0l = *(const v8s*)(bl0 + kn * 4096);
                v8s bn1l = *(const v8s*)(bl0 + kn * 4096 + 512);
                v8s ah = *(const v8s*)&s_x[a1off + kb * 16];
                v8s al = *(const v8s*)&s_x[XOFF + a1off + kb * 16];
                C1[0] = MFMA32(ah, bc0h, C1[0]);
                C1[0] = MFMA32(al, bc0h, C1[0]);
                C1[0] = MFMA32(ah, bc0l, C1[0]);
                C1[1] = MFMA32(ah, bc1h, C1[1]);
                C1[1] = MFMA32(al, bc1h, C1[1]);
                C1[1] = MFMA32(ah, bc1l, C1[1]);
                bc0h = bn0h; bc1h = bn1h; bc0l = bn0l; bc1l = bn1l;
            }
        }
        __syncthreads();   // all waves done reading x_l

        // ---- epilogue: x = sin(C1) + sin(G), G = g@(ffnA*2^l), full prec ----
        const short* gp = (lane < 32) ? s_gh : s_gl;   // h=0: g_hi, h=1: g_lo
        v8s ga = *(const v8s*)&gp[m32 * GSTRIDE + l * 8];
        #pragma unroll
        for (int t = 0; t < 2; t++) {
            v16f Z = {};
            v16f G = MFMA32(ga, (t ? gb1h : gb0h), Z);
            G = MFMA32(ga, (t ? gb1l : gb0l), G);
            const int cb = w * 64 + t * 32 + m32 + pbase;
            #pragma unroll
            for (int r = 0; r < 16; r++) {
                const int row = (r & 3) + 8 * (r >> 2) + 4 * h;
                float v = sin_rev(C1[t][r]) + sin_rev(G[r]);
                unsigned int pk = split_pack(v);
                unsigned int ppk = (unsigned int)__shfl_xor((int)pk, 1, 64);
                unsigned int dw = __builtin_amdgcn_perm(ppk, pk, psel);
                *(unsigned int*)&s_x[row * XSTRIDE + cb] = dw;
            }
        }
        __syncthreads();   // new x visible

        // ---- GEMM2: head, 3 products, 32 rows x 16 cols per wave ----
        const float b2 = bhh[l * 64 + w * 16 + i] * K5;
        v4f C2[2];
        C2[0] = (v4f){b2, b2, b2, b2};
        C2[1] = (v4f){b2, b2, b2, b2};
        {
            const short* bph = whh_hi + l * 16384 + w * 512 + lane * 8;
            const short* bpl = whh_lo + l * 16384 + w * 512 + lane * 8;
            v8s bch = *(const v8s*)(bph);
            v8s bcl = *(const v8s*)(bpl);
            #pragma unroll
            for (int kb = 0; kb < 8; kb++) {
                const int kn = (kb < 7) ? (kb + 1) : 7;
                v8s bnh = *(const v8s*)(bph + kn * 2048);
                v8s bnl = *(const v8s*)(bpl + kn * 2048);
                v8s a0h = *(const v8s*)&s_x[a2off0 + kb * 32];
                v8s a0l = *(const v8s*)&s_x[XOFF + a2off0 + kb * 32];
                v8s a1h = *(const v8s*)&s_x[a2off1 + kb * 32];
                v8s a1l = *(const v8s*)&s_x[XOFF + a2off1 + kb * 32];
                C2[0] = MFMA16(a0h, bch, C2[0]);
                C2[0] = MFMA16(a0l, bch, C2[0]);
                C2[0] = MFMA16(a0h, bcl, C2[0]);
                C2[1] = MFMA16(a1h, bch, C2[1]);
                C2[1] = MFMA16(a1l, bch, C2[1]);
                C2[1] = MFMA16(a1h, bcl, C2[1]);
                bch = bnh; bcl = bnl;
            }
        }
        #pragma unroll
        for (int m = 0; m < 2; m++)
            #pragma unroll
            for (int r = 0; r < 4; r++)
                cout[m][r] += sin_rev(C2[m][r]);
        // no barrier: next GEMM1 reads same x; overwrites after its own barrier
    }

    // ---- store x_out ----
    #pragma unroll
    for (int m = 0; m < 2; m++)
        #pragma unroll
        for (int r = 0; r < 4; r++)
            out[(row0 + m * 16 + q * 4 + r) * 64 + w * 16 + i] = cout[m][r];
}

extern "C" void kernel_launch(void* const* d_in, const int* in_sizes, int n_in,
                              void* d_out, int out_size, void* d_ws, size_t ws_size,
                              hipStream_t stream) {
    const float* pos   = (const float*)d_in[0];
    const float* gfeat = (const float*)d_in[1];
    const float* ffnA  = (const float*)d_in[2];
    const float* W0    = (const float*)d_in[3];
    const float* b0    = (const float*)d_in[4];
    const float* Wh    = (const float*)d_in[5];
    const float* bh    = (const float*)d_in[6];
    const float* Whh   = (const float*)d_in[7];
    const float* bhh   = (const float*)d_in[8];
    float* out = (float*)d_out;
    const int N = in_sizes[0] / 3;

    // ws (shorts): wh_hi 327680 | wh_lo 327680 | whh_hi 81920 | whh_lo 81920
    //              | gf_hi 20480 | gf_lo 20480   (1.72 MB total)
    short* wh_hi  = (short*)d_ws;
    short* wh_lo  = wh_hi + 327680;
    short* whh_hi = wh_lo + 327680;
    short* whh_lo = whh_hi + 81920;
    short* gf_hi  = whh_lo + 81920;
    short* gf_lo  = gf_hi + 20480;

    ffb_pack<<<210, 256, 0, stream>>>(Wh, Whh, ffnA, wh_hi, wh_lo,
                                      whh_hi, whh_lo, gf_hi, gf_lo);
    ffb_main<<<N / TM, 256, 0, stream>>>(pos, gfeat, W0, b0, bh, bhh,
                                         wh_hi, wh_lo, whh_hi, whh_lo,
                                         gf_hi, gf_lo, out);
}

// Round 6
// 363.864 us; speedup vs baseline: 2.1205x; 1.1824x over previous
//
#include <hip/hip_runtime.h>

// FFB encoder fused kernel, MI355X (gfx950). Round 6 (R5 + compile fix).
//  vs round 4: bf16 3-product -> F16 2-PRODUCT everywhere.
//   - f16 mantissa (11b) vs bf16 (8b): W single-plane f16-RNE (2^-12 rel) +
//     x hi/lo f16 split (2^-22 effective) keeps output error ~0.04 < 0.1.
//   - GEMM1: 4 MFMA32/kb (was 6), head: 4 MFMA16/kb (was 6) -> MFMA 144->106us.
//   - W_lo planes deleted -> B L2 stream halved, B reg-dbuf halved.
//   - Epilogue split uses v_cvt_pkrtz_f16_f32 (packs hi|lo in 1 instr).
//     FIX vs R5: builtin returns __fp16 ext-vector, not _Float16 -> use hw2.
//   - Grid branch keeps hi/lo on BOTH sides (A: g, B: ffnA*2^l).
//  Structure (TM=32, stride-264 LDS x planes, shfl+perm packed dword epilogue
//  writes, 32x32x16 GEMM1 / 16x16x32 head, reg double-buffered B) unchanged.

#define TM 32
#define XSTRIDE 264
#define XOFF (TM*XSTRIDE + 16)
#define GSTRIDE 48
#define K5 0.79577471545947667f         // 5/(2*pi)

typedef __attribute__((ext_vector_type(8))) _Float16 v8h;
typedef __attribute__((ext_vector_type(2))) __fp16 hw2;
typedef __attribute__((ext_vector_type(4))) float v4f;
typedef __attribute__((ext_vector_type(16))) float v16f;

#define MFMA16H(a, b, c) __builtin_amdgcn_mfma_f32_16x16x32_f16(a, b, c, 0, 0, 0)
#define MFMA32H(a, b, c) __builtin_amdgcn_mfma_f32_32x32x16_f16(a, b, c, 0, 0, 0)

__device__ __forceinline__ float sin_rev(float u) {
#if __has_builtin(__builtin_amdgcn_fractf)
    return __builtin_amdgcn_sinf(__builtin_amdgcn_fractf(u));
#else
    return __builtin_amdgcn_sinf(u - floorf(u));
#endif
}

// hot path: RTZ hi + RTZ lo, packed low16=hi high16=lo
__device__ __forceinline__ unsigned int split_pack_f16(float x) {
    hw2 c = __builtin_amdgcn_cvt_pkrtz(x, x);
    float hf = (float)c[0];
    float d = x - hf;                                  // exact
    hw2 p = __builtin_amdgcn_cvt_pkrtz(x, d);
    return __builtin_bit_cast(unsigned int, p);
}

// pack path: RNE hi + RNE lo
__device__ __forceinline__ void split_f16_rn(float x, short& h, short& l) {
    _Float16 hh = (_Float16)x;                         // RNE
    float hf = (float)hh;
    _Float16 ll = (_Float16)(x - hf);
    h = __builtin_bit_cast(short, hh);
    l = __builtin_bit_cast(short, ll);
}

// ---------------- weight packing ----------------
// wh  f16: [l][kb16][nt8][lane64][8]  (327680 shorts), scaled by K5
// whh f16: [l][kb8][nt4][lane64][8]   (81920 shorts),  scaled by K5
// gf hi/lo f16: [l][nt8][lane64][8]   (20480 shorts each), ffnA*2^l,
//               value depends on lane&31 only (k-halves duplicated)
__global__ __launch_bounds__(256) void ffb_pack(
    const float* __restrict__ Wh, const float* __restrict__ Whh,
    const float* __restrict__ ffnA,
    short* __restrict__ wh, short* __restrict__ whh,
    short* __restrict__ gf_hi, short* __restrict__ gf_lo)
{
    int t = blockIdx.x * 256 + threadIdx.x;
    if (t < 40960) {                       // (l, kb, nt, lane)
        int lane = t & 63, nt = (t >> 6) & 7, kb = (t >> 9) & 15, l = t >> 13;
        int n = nt * 32 + (lane & 31);
        int k0 = kb * 16 + (lane >> 5) * 8;
        short hs[8];
        #pragma unroll
        for (int jj = 0; jj < 8; jj++) {
            _Float16 hh = (_Float16)(Wh[(l * 256 + k0 + jj) * 256 + n] * K5);
            hs[jj] = __builtin_bit_cast(short, hh);
        }
        *(v8h*)(wh + t * 8) = *(v8h*)hs;
    } else if (t < 51200) {
        int t2 = t - 40960;                // (l, kb, nt, lane)
        int lane = t2 & 63, nt = (t2 >> 6) & 3, kb = (t2 >> 8) & 7, l = t2 >> 11;
        int n = nt * 16 + (lane & 15);
        int k0 = kb * 32 + (lane >> 4) * 8;
        short hs[8];
        #pragma unroll
        for (int jj = 0; jj < 8; jj++) {
            _Float16 hh = (_Float16)(Whh[(l * 256 + k0 + jj) * 64 + n] * K5);
            hs[jj] = __builtin_bit_cast(short, hh);
        }
        *(v8h*)(whh + t2 * 8) = *(v8h*)hs;
    } else if (t < 53760) {
        int t3 = t - 51200;                // (l, nt, lane)
        int lane = t3 & 63, nt = (t3 >> 6) & 7, l = t3 >> 9;
        int n = nt * 32 + (lane & 31);
        short hs[8], ls[8];
        #pragma unroll
        for (int jj = 0; jj < 8; jj++)
            split_f16_rn(ffnA[(l * 8 + jj) * 256 + n] * (float)(1 << l),
                         hs[jj], ls[jj]);
        *(v8h*)(gf_hi + t3 * 8) = *(v8h*)hs;
        *(v8h*)(gf_lo + t3 * 8) = *(v8h*)ls;
    }
}

// ---------------- main fused kernel ----------------
__global__ __launch_bounds__(256, 4) void ffb_main(
    const float* __restrict__ pos, const float* __restrict__ gfeat,
    const float* __restrict__ W0, const float* __restrict__ b0,
    const float* __restrict__ bh, const float* __restrict__ bhh,
    const short* __restrict__ wh, const short* __restrict__ whh,
    const short* __restrict__ gf_hi, const short* __restrict__ gf_lo,
    float* __restrict__ out)
{
    __shared__ __align__(16) short s_x[2 * TM * XSTRIDE + 16];  // hi @0, lo @XOFF
    __shared__ __align__(16) short s_gh[TM * GSTRIDE];
    __shared__ __align__(16) short s_gl[TM * GSTRIDE];
    __shared__ float s_pos[TM * 3];

    const int tid = threadIdx.x;
    const int row0 = blockIdx.x * TM;
    const int lane = tid & 63;
    const int w = tid >> 6;
    const int i = lane & 15;
    const int q = lane >> 4;
    const int m32 = lane & 31;
    const int h = lane >> 5;

    const unsigned int psel = (lane & 1) ? 0x03020706u : 0x05040100u;
    const int pbase = (lane & 1) ? (XOFF - 1) : 0;

    if (tid < TM * 3) s_pos[tid] = pos[row0 * 3 + tid];
    for (int k2 = tid; k2 < TM * 40; k2 += 256) {
        int r = k2 / 40, f = k2 % 40;
        unsigned int dw = split_pack_f16(gfeat[row0 * 40 + k2]);
        s_gh[r * GSTRIDE + f] = (short)(dw & 0xffffu);
        s_gl[r * GSTRIDE + f] = (short)(dw >> 16);
    }
    __syncthreads();

    // layer 0: x = sin(5*(pos@W0 + b0))
    {
        const int c = tid;
        const float w00 = W0[c], w01 = W0[256 + c], w02 = W0[512 + c], bc = b0[c];
        #pragma unroll 4
        for (int r = 0; r < TM; r++) {
            float d = s_pos[r * 3 + 0] * w00 + s_pos[r * 3 + 1] * w01
                    + s_pos[r * 3 + 2] * w02 + bc;
            unsigned int dw = split_pack_f16(sin_rev(d * K5));
            s_x[r * XSTRIDE + c] = (short)(dw & 0xffffu);
            s_x[XOFF + r * XSTRIDE + c] = (short)(dw >> 16);
        }
    }
    __syncthreads();

    float cout[2][4];
    #pragma unroll
    for (int m = 0; m < 2; m++)
        #pragma unroll
        for (int r = 0; r < 4; r++) cout[m][r] = 0.f;

    const int a1off = m32 * XSTRIDE + h * 8;               // + kb*16 (GEMM1)
    const int a2off0 = i * XSTRIDE + q * 8;                // + kb*32 (GEMM2)
    const int a2off1 = (16 + i) * XSTRIDE + q * 8;

    for (int l = 0; l < 5; l++) {
        // ---- bias-init C1 (pre-scaled by K5), prefetch G B-frags ----
        const float bias0 = bh[l * 256 + w * 64 + m32] * K5;
        const float bias1 = bh[l * 256 + w * 64 + 32 + m32] * K5;
        v16f C1[2];
        #pragma unroll
        for (int r = 0; r < 16; r++) { C1[0][r] = bias0; C1[1][r] = bias1; }
        v8h gb0h = *(const v8h*)(gf_hi + ((l * 8 + w * 2 + 0) * 64 + lane) * 8);
        v8h gb1h = *(const v8h*)(gf_hi + ((l * 8 + w * 2 + 1) * 64 + lane) * 8);
        v8h gb0l = *(const v8h*)(gf_lo + ((l * 8 + w * 2 + 0) * 64 + lane) * 8);
        v8h gb1l = *(const v8h*)(gf_lo + ((l * 8 + w * 2 + 1) * 64 + lane) * 8);

        // ---- GEMM1: 32 rows x 64 cols per wave, 32x32x16 f16, 2 products ----
        {
            const short* bp = wh + l * 65536 + (2 * w) * 512 + lane * 8;
            v8h bc0 = *(const v8h*)(bp);
            v8h bc1 = *(const v8h*)(bp + 512);
            #pragma unroll
            for (int kb = 0; kb < 16; kb++) {
                const int kn = (kb < 15) ? (kb + 1) : 15;
                v8h bn0 = *(const v8h*)(bp + kn * 4096);
                v8h bn1 = *(const v8h*)(bp + kn * 4096 + 512);
                v8h ah = *(const v8h*)&s_x[a1off + kb * 16];
                v8h al = *(const v8h*)&s_x[XOFF + a1off + kb * 16];
                C1[0] = MFMA32H(ah, bc0, C1[0]);
                C1[0] = MFMA32H(al, bc0, C1[0]);
                C1[1] = MFMA32H(ah, bc1, C1[1]);
                C1[1] = MFMA32H(al, bc1, C1[1]);
                bc0 = bn0; bc1 = bn1;
            }
        }
        __syncthreads();   // all waves done reading x_l

        // ---- epilogue: x = sin(C1) + sin(G), G = g@(ffnA*2^l) ----
        const short* gp = (lane < 32) ? s_gh : s_gl;   // k-half 0: g_hi, 1: g_lo
        v8h ga = *(const v8h*)&gp[m32 * GSTRIDE + l * 8];
        #pragma unroll
        for (int t = 0; t < 2; t++) {
            v16f Z = {};
            v16f G = MFMA32H(ga, (t ? gb1h : gb0h), Z);
            G = MFMA32H(ga, (t ? gb1l : gb0l), G);
            const int cb = w * 64 + t * 32 + m32 + pbase;
            #pragma unroll
            for (int r = 0; r < 16; r++) {
                const int row = (r & 3) + 8 * (r >> 2) + 4 * h;
                float v = sin_rev(C1[t][r]) + sin_rev(G[r]);
                unsigned int pk = split_pack_f16(v);
                unsigned int ppk = (unsigned int)__shfl_xor((int)pk, 1, 64);
                unsigned int dw = __builtin_amdgcn_perm(ppk, pk, psel);
                *(unsigned int*)&s_x[row * XSTRIDE + cb] = dw;
            }
        }
        __syncthreads();   // new x visible

        // ---- GEMM2: head, f16 2-product, 32 rows x 16 cols per wave ----
        const float b2 = bhh[l * 64 + w * 16 + i] * K5;
        v4f C2[2];
        C2[0] = (v4f){b2, b2, b2, b2};
        C2[1] = (v4f){b2, b2, b2, b2};
        {
            const short* bp = whh + l * 16384 + w * 512 + lane * 8;
            v8h bc = *(const v8h*)(bp);
            #pragma unroll
            for (int kb = 0; kb < 8; kb++) {
                const int kn = (kb < 7) ? (kb + 1) : 7;
                v8h bn = *(const v8h*)(bp + kn * 2048);
                v8h a0h = *(const v8h*)&s_x[a2off0 + kb * 32];
                v8h a0l = *(const v8h*)&s_x[XOFF + a2off0 + kb * 32];
                v8h a1h = *(const v8h*)&s_x[a2off1 + kb * 32];
                v8h a1l = *(const v8h*)&s_x[XOFF + a2off1 + kb * 32];
                C2[0] = MFMA16H(a0h, bc, C2[0]);
                C2[0] = MFMA16H(a0l, bc, C2[0]);
                C2[1] = MFMA16H(a1h, bc, C2[1]);
                C2[1] = MFMA16H(a1l, bc, C2[1]);
                bc = bn;
            }
        }
        #pragma unroll
        for (int m = 0; m < 2; m++)
            #pragma unroll
            for (int r = 0; r < 4; r++)
                cout[m][r] += sin_rev(C2[m][r]);
        // no barrier: next GEMM1 reads same x; overwrites after its own barrier
    }

    // ---- store x_out ----
    #pragma unroll
    for (int m = 0; m < 2; m++)
        #pragma unroll
        for (int r = 0; r < 4; r++)
            out[(row0 + m * 16 + q * 4 + r) * 64 + w * 16 + i] = cout[m][r];
}

extern "C" void kernel_launch(void* const* d_in, const int* in_sizes, int n_in,
                              void* d_out, int out_size, void* d_ws, size_t ws_size,
                              hipStream_t stream) {
    const float* pos   = (const float*)d_in[0];
    const float* gfeat = (const float*)d_in[1];
    const float* ffnA  = (const float*)d_in[2];
    const float* W0    = (const float*)d_in[3];
    const float* b0    = (const float*)d_in[4];
    const float* Wh    = (const float*)d_in[5];
    const float* bh    = (const float*)d_in[6];
    const float* Whh   = (const float*)d_in[7];
    const float* bhh   = (const float*)d_in[8];
    float* out = (float*)d_out;
    const int N = in_sizes[0] / 3;

    // ws (shorts): wh 327680 | whh 81920 | gf_hi 20480 | gf_lo 20480  (0.90 MB)
    short* wh    = (short*)d_ws;
    short* whh   = wh + 327680;
    short* gf_hi = whh + 81920;
    short* gf_lo = gf_hi + 20480;

    ffb_pack<<<210, 256, 0, stream>>>(Wh, Whh, ffnA, wh, whh, gf_hi, gf_lo);
    ffb_main<<<N / TM, 256, 0, stream>>>(pos, gfeat, W0, b0, bh, bhh,
                                         wh, whh, gf_hi, gf_lo, out);
}

// Round 7
// 265.251 us; speedup vs baseline: 2.9089x; 1.3718x over previous
//
#include <hip/hip_runtime.h>

// FFB encoder fused kernel, MI355X (gfx950). Round 7.
//  vs round 6: SINGLE-PRODUCT f16 GEMMs (x_lo plane deleted).
//   - Evidence: R4->R6 W-side f16 quant added only +0.016 absmax; x-side
//     f16-RNE quant is symmetric (sum eps_x*w vs sum x*eps_w) -> predict
//     absmax ~0.065 < 0.1 threshold.
//   - GEMM1: 2 MFMA32/kb (was 4), head: 2 MFMA16/kb (was 4) -> MFMA floor
//     104 -> 54 us. A-side ds_reads halve.
//   - x LDS: one f16 plane (16.9 KB); total LDS 23.4 KB -> 6 blocks/CU
//     (was 4 at 40.4 KB) -> better barrier hiding.
//   - Epilogue: sin+sin+add+cvt_f16(RNE)+ds_write_b16 per output; shfl/perm
//     dword packing deleted (b16 writes: 2 lanes/bank same-dword = 2-way =
//     free; h=0/h=1 row groups hit disjoint bank halves).
//   - Grid branch keeps hi/lo on BOTH sides (A: g, B: ffnA*2^l) - 4 MFMA/layer.
//  Structure (TM=32, stride-264 LDS, 32x32x16 GEMM1 / 16x16x32 head,
//  reg double-buffered B streams) unchanged.

#define TM 32
#define XSTRIDE 264
#define GSTRIDE 48
#define K5 0.79577471545947667f         // 5/(2*pi)

typedef __attribute__((ext_vector_type(8))) _Float16 v8h;
typedef __attribute__((ext_vector_type(2))) __fp16 hw2;
typedef __attribute__((ext_vector_type(4))) float v4f;
typedef __attribute__((ext_vector_type(16))) float v16f;

#define MFMA16H(a, b, c) __builtin_amdgcn_mfma_f32_16x16x32_f16(a, b, c, 0, 0, 0)
#define MFMA32H(a, b, c) __builtin_amdgcn_mfma_f32_32x32x16_f16(a, b, c, 0, 0, 0)

__device__ __forceinline__ float sin_rev(float u) {
#if __has_builtin(__builtin_amdgcn_fractf)
    return __builtin_amdgcn_sinf(__builtin_amdgcn_fractf(u));
#else
    return __builtin_amdgcn_sinf(u - floorf(u));
#endif
}

__device__ __forceinline__ short f16s(float x) {      // RNE f32->f16
    _Float16 hh = (_Float16)x;
    return __builtin_bit_cast(short, hh);
}

// RTZ hi + RNE-ish lo pair (grid feats staging; lo compensates hi exactly)
__device__ __forceinline__ unsigned int split_pack_f16(float x) {
    hw2 c = __builtin_amdgcn_cvt_pkrtz(x, x);
    float hf = (float)c[0];
    float d = x - hf;                                  // exact
    hw2 p = __builtin_amdgcn_cvt_pkrtz(x, d);
    return __builtin_bit_cast(unsigned int, p);
}

__device__ __forceinline__ void split_f16_rn(float x, short& h, short& l) {
    _Float16 hh = (_Float16)x;                         // RNE
    float hf = (float)hh;
    _Float16 ll = (_Float16)(x - hf);
    h = __builtin_bit_cast(short, hh);
    l = __builtin_bit_cast(short, ll);
}

// ---------------- weight packing (unchanged from R6) ----------------
// wh  f16: [l][kb16][nt8][lane64][8]  (327680 shorts), scaled by K5
// whh f16: [l][kb8][nt4][lane64][8]   (81920 shorts),  scaled by K5
// gf hi/lo f16: [l][nt8][lane64][8]   (20480 shorts each), ffnA*2^l
__global__ __launch_bounds__(256) void ffb_pack(
    const float* __restrict__ Wh, const float* __restrict__ Whh,
    const float* __restrict__ ffnA,
    short* __restrict__ wh, short* __restrict__ whh,
    short* __restrict__ gf_hi, short* __restrict__ gf_lo)
{
    int t = blockIdx.x * 256 + threadIdx.x;
    if (t < 40960) {                       // (l, kb, nt, lane)
        int lane = t & 63, nt = (t >> 6) & 7, kb = (t >> 9) & 15, l = t >> 13;
        int n = nt * 32 + (lane & 31);
        int k0 = kb * 16 + (lane >> 5) * 8;
        short hs[8];
        #pragma unroll
        for (int jj = 0; jj < 8; jj++)
            hs[jj] = f16s(Wh[(l * 256 + k0 + jj) * 256 + n] * K5);
        *(v8h*)(wh + t * 8) = *(v8h*)hs;
    } else if (t < 51200) {
        int t2 = t - 40960;                // (l, kb, nt, lane)
        int lane = t2 & 63, nt = (t2 >> 6) & 3, kb = (t2 >> 8) & 7, l = t2 >> 11;
        int n = nt * 16 + (lane & 15);
        int k0 = kb * 32 + (lane >> 4) * 8;
        short hs[8];
        #pragma unroll
        for (int jj = 0; jj < 8; jj++)
            hs[jj] = f16s(Whh[(l * 256 + k0 + jj) * 64 + n] * K5);
        *(v8h*)(whh + t2 * 8) = *(v8h*)hs;
    } else if (t < 53760) {
        int t3 = t - 51200;                // (l, nt, lane)
        int lane = t3 & 63, nt = (t3 >> 6) & 7, l = t3 >> 9;
        int n = nt * 32 + (lane & 31);
        short hs[8], ls[8];
        #pragma unroll
        for (int jj = 0; jj < 8; jj++)
            split_f16_rn(ffnA[(l * 8 + jj) * 256 + n] * (float)(1 << l),
                         hs[jj], ls[jj]);
        *(v8h*)(gf_hi + t3 * 8) = *(v8h*)hs;
        *(v8h*)(gf_lo + t3 * 8) = *(v8h*)ls;
    }
}

// ---------------- main fused kernel ----------------
__global__ __launch_bounds__(256, 4) void ffb_main(
    const float* __restrict__ pos, const float* __restrict__ gfeat,
    const float* __restrict__ W0, const float* __restrict__ b0,
    const float* __restrict__ bh, const float* __restrict__ bhh,
    const short* __restrict__ wh, const short* __restrict__ whh,
    const short* __restrict__ gf_hi, const short* __restrict__ gf_lo,
    float* __restrict__ out)
{
    __shared__ __align__(16) short s_x[TM * XSTRIDE];   // f16, single plane
    __shared__ __align__(16) short s_gh[TM * GSTRIDE];
    __shared__ __align__(16) short s_gl[TM * GSTRIDE];
    __shared__ float s_pos[TM * 3];

    const int tid = threadIdx.x;
    const int row0 = blockIdx.x * TM;
    const int lane = tid & 63;
    const int w = tid >> 6;
    const int i = lane & 15;
    const int q = lane >> 4;
    const int m32 = lane & 31;
    const int h = lane >> 5;

    if (tid < TM * 3) s_pos[tid] = pos[row0 * 3 + tid];
    for (int k2 = tid; k2 < TM * 40; k2 += 256) {
        int r = k2 / 40, f = k2 % 40;
        unsigned int dw = split_pack_f16(gfeat[row0 * 40 + k2]);
        s_gh[r * GSTRIDE + f] = (short)(dw & 0xffffu);
        s_gl[r * GSTRIDE + f] = (short)(dw >> 16);
    }
    __syncthreads();

    // layer 0: x = sin(5*(pos@W0 + b0))
    {
        const int c = tid;
        const float w00 = W0[c], w01 = W0[256 + c], w02 = W0[512 + c], bc = b0[c];
        #pragma unroll 4
        for (int r = 0; r < TM; r++) {
            float d = s_pos[r * 3 + 0] * w00 + s_pos[r * 3 + 1] * w01
                    + s_pos[r * 3 + 2] * w02 + bc;
            s_x[r * XSTRIDE + c] = f16s(sin_rev(d * K5));
        }
    }
    __syncthreads();

    float cout[2][4];
    #pragma unroll
    for (int m = 0; m < 2; m++)
        #pragma unroll
        for (int r = 0; r < 4; r++) cout[m][r] = 0.f;

    const int a1off = m32 * XSTRIDE + h * 8;               // + kb*16 (GEMM1)
    const int a2off0 = i * XSTRIDE + q * 8;                // + kb*32 (GEMM2)
    const int a2off1 = (16 + i) * XSTRIDE + q * 8;

    for (int l = 0; l < 5; l++) {
        // ---- bias-init C1 (pre-scaled by K5), prefetch G B-frags ----
        const float bias0 = bh[l * 256 + w * 64 + m32] * K5;
        const float bias1 = bh[l * 256 + w * 64 + 32 + m32] * K5;
        v16f C1[2];
        #pragma unroll
        for (int r = 0; r < 16; r++) { C1[0][r] = bias0; C1[1][r] = bias1; }
        v8h gb0h = *(const v8h*)(gf_hi + ((l * 8 + w * 2 + 0) * 64 + lane) * 8);
        v8h gb1h = *(const v8h*)(gf_hi + ((l * 8 + w * 2 + 1) * 64 + lane) * 8);
        v8h gb0l = *(const v8h*)(gf_lo + ((l * 8 + w * 2 + 0) * 64 + lane) * 8);
        v8h gb1l = *(const v8h*)(gf_lo + ((l * 8 + w * 2 + 1) * 64 + lane) * 8);

        // ---- GEMM1: 32 rows x 64 cols per wave, 32x32x16 f16, 1 product ----
        {
            const short* bp = wh + l * 65536 + (2 * w) * 512 + lane * 8;
            v8h bc0 = *(const v8h*)(bp);
            v8h bc1 = *(const v8h*)(bp + 512);
            #pragma unroll
            for (int kb = 0; kb < 16; kb++) {
                const int kn = (kb < 15) ? (kb + 1) : 15;
                v8h bn0 = *(const v8h*)(bp + kn * 4096);
                v8h bn1 = *(const v8h*)(bp + kn * 4096 + 512);
                v8h ah = *(const v8h*)&s_x[a1off + kb * 16];
                C1[0] = MFMA32H(ah, bc0, C1[0]);
                C1[1] = MFMA32H(ah, bc1, C1[1]);
                bc0 = bn0; bc1 = bn1;
            }
        }
        __syncthreads();   // all waves done reading x_l

        // ---- epilogue: x = sin(C1) + sin(G), G = g@(ffnA*2^l) ----
        const short* gp = (lane < 32) ? s_gh : s_gl;   // k-half 0: g_hi, 1: g_lo
        v8h ga = *(const v8h*)&gp[m32 * GSTRIDE + l * 8];
        #pragma unroll
        for (int t = 0; t < 2; t++) {
            v16f Z = {};
            v16f G = MFMA32H(ga, (t ? gb1h : gb0h), Z);
            G = MFMA32H(ga, (t ? gb1l : gb0l), G);
            const int col = w * 64 + t * 32 + m32;
            #pragma unroll
            for (int r = 0; r < 16; r++) {
                const int row = (r & 3) + 8 * (r >> 2) + 4 * h;
                float v = sin_rev(C1[t][r]) + sin_rev(G[r]);
                s_x[row * XSTRIDE + col] = f16s(v);
            }
        }
        __syncthreads();   // new x visible

        // ---- GEMM2: head, f16 1-product, 32 rows x 16 cols per wave ----
        const float b2 = bhh[l * 64 + w * 16 + i] * K5;
        v4f C2[2];
        C2[0] = (v4f){b2, b2, b2, b2};
        C2[1] = (v4f){b2, b2, b2, b2};
        {
            const short* bp = whh + l * 16384 + w * 512 + lane * 8;
            v8h bc = *(const v8h*)(bp);
            #pragma unroll
            for (int kb = 0; kb < 8; kb++) {
                const int kn = (kb < 7) ? (kb + 1) : 7;
                v8h bn = *(const v8h*)(bp + kn * 2048);
                v8h a0 = *(const v8h*)&s_x[a2off0 + kb * 32];
                v8h a1 = *(const v8h*)&s_x[a2off1 + kb * 32];
                C2[0] = MFMA16H(a0, bc, C2[0]);
                C2[1] = MFMA16H(a1, bc, C2[1]);
                bc = bn;
            }
        }
        #pragma unroll
        for (int m = 0; m < 2; m++)
            #pragma unroll
            for (int r = 0; r < 4; r++)
                cout[m][r] += sin_rev(C2[m][r]);
        // no barrier: next GEMM1 reads same x; overwrites after its own barrier
    }

    // ---- store x_out ----
    #pragma unroll
    for (int m = 0; m < 2; m++)
        #pragma unroll
        for (int r = 0; r < 4; r++)
            out[(row0 + m * 16 + q * 4 + r) * 64 + w * 16 + i] = cout[m][r];
}

extern "C" void kernel_launch(void* const* d_in, const int* in_sizes, int n_in,
                              void* d_out, int out_size, void* d_ws, size_t ws_size,
                              hipStream_t stream) {
    const float* pos   = (const float*)d_in[0];
    const float* gfeat = (const float*)d_in[1];
    const float* ffnA  = (const float*)d_in[2];
    const float* W0    = (const float*)d_in[3];
    const float* b0    = (const float*)d_in[4];
    const float* Wh    = (const float*)d_in[5];
    const float* bh    = (const float*)d_in[6];
    const float* Whh   = (const float*)d_in[7];
    const float* bhh   = (const float*)d_in[8];
    float* out = (float*)d_out;
    const int N = in_sizes[0] / 3;

    // ws (shorts): wh 327680 | whh 81920 | gf_hi 20480 | gf_lo 20480  (0.90 MB)
    short* wh    = (short*)d_ws;
    short* whh   = wh + 327680;
    short* gf_hi = whh + 81920;
    short* gf_lo = gf_hi + 20480;

    ffb_pack<<<210, 256, 0, stream>>>(Wh, Whh, ffnA, wh, whh, gf_hi, gf_lo);
    ffb_main<<<N / TM, 256, 0, stream>>>(pos, gfeat, W0, b0, bh, bhh,
                                         wh, whh, gf_hi, gf_lo, out);
}

// Round 8
// 249.251 us; speedup vs baseline: 3.0956x; 1.0642x over previous
//
#include <hip/hip_runtime.h>

// FFB encoder fused kernel, MI355X (gfx950). Round 8.
//  vs round 7: TM=64 (same 256 threads) + 2-deep B prefetch.
//   - Each wave: 64 rows x 64 cols in GEMM1 -> 4 MFMA32 per B-frag pair
//     (was 2): 2x MFMA per loaded B-byte and per L2-latency window.
//   - Blocks 4096 -> 2048: B L2 traffic 3.2 -> 1.6 GB; barrier count per
//     row halves.
//   - GEMM1 B stream prefetched 2 kb ahead (ring of 3, fully unrolled).
//   - Head: 4 16-row m-tiles per wave; B loaded once per block per layer.
//   - LDS 46.8 KB -> 3 blocks/CU; __launch_bounds__(256,3).
//  Numerics identical to R7 (f16 single-product GEMMs, hi/lo grid branch):
//  absmax 0.0625 expected unchanged.

#define TM 64
#define XSTRIDE 264
#define GSTRIDE 48
#define K5 0.79577471545947667f         // 5/(2*pi)

typedef __attribute__((ext_vector_type(8))) _Float16 v8h;
typedef __attribute__((ext_vector_type(2))) __fp16 hw2;
typedef __attribute__((ext_vector_type(4))) float v4f;
typedef __attribute__((ext_vector_type(16))) float v16f;

#define MFMA16H(a, b, c) __builtin_amdgcn_mfma_f32_16x16x32_f16(a, b, c, 0, 0, 0)
#define MFMA32H(a, b, c) __builtin_amdgcn_mfma_f32_32x32x16_f16(a, b, c, 0, 0, 0)

__device__ __forceinline__ float sin_rev(float u) {
#if __has_builtin(__builtin_amdgcn_fractf)
    return __builtin_amdgcn_sinf(__builtin_amdgcn_fractf(u));
#else
    return __builtin_amdgcn_sinf(u - floorf(u));
#endif
}

__device__ __forceinline__ short f16s(float x) {      // RNE f32->f16
    _Float16 hh = (_Float16)x;
    return __builtin_bit_cast(short, hh);
}

// RTZ hi + lo pair packed (grid feats staging; lo compensates hi exactly)
__device__ __forceinline__ unsigned int split_pack_f16(float x) {
    hw2 c = __builtin_amdgcn_cvt_pkrtz(x, x);
    float hf = (float)c[0];
    float d = x - hf;                                  // exact
    hw2 p = __builtin_amdgcn_cvt_pkrtz(x, d);
    return __builtin_bit_cast(unsigned int, p);
}

__device__ __forceinline__ void split_f16_rn(float x, short& h, short& l) {
    _Float16 hh = (_Float16)x;                         // RNE
    float hf = (float)hh;
    _Float16 ll = (_Float16)(x - hf);
    h = __builtin_bit_cast(short, hh);
    l = __builtin_bit_cast(short, ll);
}

// ---------------- weight packing (unchanged from R7) ----------------
// wh  f16: [l][kb16][nt8][lane64][8]  (327680 shorts), scaled by K5
// whh f16: [l][kb8][nt4][lane64][8]   (81920 shorts),  scaled by K5
// gf hi/lo f16: [l][nt8][lane64][8]   (20480 shorts each), ffnA*2^l
__global__ __launch_bounds__(256) void ffb_pack(
    const float* __restrict__ Wh, const float* __restrict__ Whh,
    const float* __restrict__ ffnA,
    short* __restrict__ wh, short* __restrict__ whh,
    short* __restrict__ gf_hi, short* __restrict__ gf_lo)
{
    int t = blockIdx.x * 256 + threadIdx.x;
    if (t < 40960) {                       // (l, kb, nt, lane)
        int lane = t & 63, nt = (t >> 6) & 7, kb = (t >> 9) & 15, l = t >> 13;
        int n = nt * 32 + (lane & 31);
        int k0 = kb * 16 + (lane >> 5) * 8;
        short hs[8];
        #pragma unroll
        for (int jj = 0; jj < 8; jj++)
            hs[jj] = f16s(Wh[(l * 256 + k0 + jj) * 256 + n] * K5);
        *(v8h*)(wh + t * 8) = *(v8h*)hs;
    } else if (t < 51200) {
        int t2 = t - 40960;                // (l, kb, nt, lane)
        int lane = t2 & 63, nt = (t2 >> 6) & 3, kb = (t2 >> 8) & 7, l = t2 >> 11;
        int n = nt * 16 + (lane & 15);
        int k0 = kb * 32 + (lane >> 4) * 8;
        short hs[8];
        #pragma unroll
        for (int jj = 0; jj < 8; jj++)
            hs[jj] = f16s(Whh[(l * 256 + k0 + jj) * 64 + n] * K5);
        *(v8h*)(whh + t2 * 8) = *(v8h*)hs;
    } else if (t < 53760) {
        int t3 = t - 51200;                // (l, nt, lane)
        int lane = t3 & 63, nt = (t3 >> 6) & 7, l = t3 >> 9;
        int n = nt * 32 + (lane & 31);
        short hs[8], ls[8];
        #pragma unroll
        for (int jj = 0; jj < 8; jj++)
            split_f16_rn(ffnA[(l * 8 + jj) * 256 + n] * (float)(1 << l),
                         hs[jj], ls[jj]);
        *(v8h*)(gf_hi + t3 * 8) = *(v8h*)hs;
        *(v8h*)(gf_lo + t3 * 8) = *(v8h*)ls;
    }
}

// ---------------- main fused kernel ----------------
__global__ __launch_bounds__(256, 3) void ffb_main(
    const float* __restrict__ pos, const float* __restrict__ gfeat,
    const float* __restrict__ W0, const float* __restrict__ b0,
    const float* __restrict__ bh, const float* __restrict__ bhh,
    const short* __restrict__ wh, const short* __restrict__ whh,
    const short* __restrict__ gf_hi, const short* __restrict__ gf_lo,
    float* __restrict__ out)
{
    __shared__ __align__(16) short s_x[TM * XSTRIDE];   // f16, single plane
    __shared__ __align__(16) short s_gh[TM * GSTRIDE];
    __shared__ __align__(16) short s_gl[TM * GSTRIDE];
    __shared__ float s_pos[TM * 3];

    const int tid = threadIdx.x;
    const int row0 = blockIdx.x * TM;
    const int lane = tid & 63;
    const int w = tid >> 6;
    const int i = lane & 15;
    const int q = lane >> 4;
    const int m32 = lane & 31;
    const int h = lane >> 5;

    if (tid < TM * 3) s_pos[tid] = pos[row0 * 3 + tid];
    for (int k2 = tid; k2 < TM * 40; k2 += 256) {
        int r = k2 / 40, f = k2 % 40;
        unsigned int dw = split_pack_f16(gfeat[row0 * 40 + k2]);
        s_gh[r * GSTRIDE + f] = (short)(dw & 0xffffu);
        s_gl[r * GSTRIDE + f] = (short)(dw >> 16);
    }
    __syncthreads();

    // layer 0: x = sin(5*(pos@W0 + b0))
    {
        const int c = tid;
        const float w00 = W0[c], w01 = W0[256 + c], w02 = W0[512 + c], bc = b0[c];
        #pragma unroll 4
        for (int r = 0; r < TM; r++) {
            float d = s_pos[r * 3 + 0] * w00 + s_pos[r * 3 + 1] * w01
                    + s_pos[r * 3 + 2] * w02 + bc;
            s_x[r * XSTRIDE + c] = f16s(sin_rev(d * K5));
        }
    }
    __syncthreads();

    float cout[4][4];
    #pragma unroll
    for (int m = 0; m < 4; m++)
        #pragma unroll
        for (int r = 0; r < 4; r++) cout[m][r] = 0.f;

    const int a1off0 = m32 * XSTRIDE + h * 8;            // m-tile 0, + kb*16
    const int a1off1 = (32 + m32) * XSTRIDE + h * 8;     // m-tile 1

    for (int l = 0; l < 5; l++) {
        // ---- bias-init C1 (pre-scaled by K5), prefetch G B-frags ----
        const float bias0 = bh[l * 256 + w * 64 + m32] * K5;
        const float bias1 = bh[l * 256 + w * 64 + 32 + m32] * K5;
        v16f C1[2][2];
        #pragma unroll
        for (int r = 0; r < 16; r++) {
            C1[0][0][r] = bias0; C1[1][0][r] = bias0;
            C1[0][1][r] = bias1; C1[1][1][r] = bias1;
        }
        v8h gb0h = *(const v8h*)(gf_hi + ((l * 8 + w * 2 + 0) * 64 + lane) * 8);
        v8h gb1h = *(const v8h*)(gf_hi + ((l * 8 + w * 2 + 1) * 64 + lane) * 8);
        v8h gb0l = *(const v8h*)(gf_lo + ((l * 8 + w * 2 + 0) * 64 + lane) * 8);
        v8h gb1l = *(const v8h*)(gf_lo + ((l * 8 + w * 2 + 1) * 64 + lane) * 8);

        // ---- GEMM1: 64 rows x 64 cols per wave, 2-deep B prefetch ----
        {
            const short* bp = wh + l * 65536 + (2 * w) * 512 + lane * 8;
            v8h rb0[3], rb1[3];
            rb0[0] = *(const v8h*)(bp);
            rb1[0] = *(const v8h*)(bp + 512);
            rb0[1] = *(const v8h*)(bp + 4096);
            rb1[1] = *(const v8h*)(bp + 4096 + 512);
            #pragma unroll
            for (int kb = 0; kb < 16; kb++) {
                if (kb + 2 < 16) {
                    rb0[(kb + 2) % 3] = *(const v8h*)(bp + (kb + 2) * 4096);
                    rb1[(kb + 2) % 3] = *(const v8h*)(bp + (kb + 2) * 4096 + 512);
                }
                v8h a0 = *(const v8h*)&s_x[a1off0 + kb * 16];
                v8h a1 = *(const v8h*)&s_x[a1off1 + kb * 16];
                v8h bc0 = rb0[kb % 3], bc1 = rb1[kb % 3];
                C1[0][0] = MFMA32H(a0, bc0, C1[0][0]);
                C1[0][1] = MFMA32H(a0, bc1, C1[0][1]);
                C1[1][0] = MFMA32H(a1, bc0, C1[1][0]);
                C1[1][1] = MFMA32H(a1, bc1, C1[1][1]);
            }
        }
        __syncthreads();   // all waves done reading x_l

        // ---- epilogue: x = sin(C1) + sin(G), G = g@(ffnA*2^l) ----
        const short* gp = (lane < 32) ? s_gh : s_gl;   // k-half 0: g_hi, 1: g_lo
        #pragma unroll
        for (int m = 0; m < 2; m++) {
            v8h ga = *(const v8h*)&gp[(m * 32 + m32) * GSTRIDE + l * 8];
            #pragma unroll
            for (int t = 0; t < 2; t++) {
                v16f Z = {};
                v16f G = MFMA32H(ga, (t ? gb1h : gb0h), Z);
                G = MFMA32H(ga, (t ? gb1l : gb0l), G);
                const int col = w * 64 + t * 32 + m32;
                #pragma unroll
                for (int r = 0; r < 16; r++) {
                    const int row = m * 32 + (r & 3) + 8 * (r >> 2) + 4 * h;
                    float v = sin_rev(C1[m][t][r]) + sin_rev(G[r]);
                    s_x[row * XSTRIDE + col] = f16s(v);
                }
            }
        }
        __syncthreads();   // new x visible

        // ---- GEMM2: head, 64 rows x 16 cols per wave (4 m-tiles) ----
        const float b2 = bhh[l * 64 + w * 16 + i] * K5;
        v4f C2[4];
        #pragma unroll
        for (int m = 0; m < 4; m++) C2[m] = (v4f){b2, b2, b2, b2};
        {
            const short* bp = whh + l * 16384 + w * 512 + lane * 8;
            v8h bc = *(const v8h*)(bp);
            #pragma unroll
            for (int kb = 0; kb < 8; kb++) {
                const int kn = (kb < 7) ? (kb + 1) : 7;
                v8h bn = *(const v8h*)(bp + kn * 2048);
                #pragma unroll
                for (int m = 0; m < 4; m++) {
                    v8h a = *(const v8h*)&s_x[(m * 16 + i) * XSTRIDE + q * 8 + kb * 32];
                    C2[m] = MFMA16H(a, bc, C2[m]);
                }
                bc = bn;
            }
        }
        #pragma unroll
        for (int m = 0; m < 4; m++)
            #pragma unroll
            for (int r = 0; r < 4; r++)
                cout[m][r] += sin_rev(C2[m][r]);
        // no barrier: next GEMM1 reads same x; overwrites after its own barrier
    }

    // ---- store x_out ----
    #pragma unroll
    for (int m = 0; m < 4; m++)
        #pragma unroll
        for (int r = 0; r < 4; r++)
            out[(row0 + m * 16 + q * 4 + r) * 64 + w * 16 + i] = cout[m][r];
}

extern "C" void kernel_launch(void* const* d_in, const int* in_sizes, int n_in,
                              void* d_out, int out_size, void* d_ws, size_t ws_size,
                              hipStream_t stream) {
    const float* pos   = (const float*)d_in[0];
    const float* gfeat = (const float*)d_in[1];
    const float* ffnA  = (const float*)d_in[2];
    const float* W0    = (const float*)d_in[3];
    const float* b0    = (const float*)d_in[4];
    const float* Wh    = (const float*)d_in[5];
    const float* bh    = (const float*)d_in[6];
    const float* Whh   = (const float*)d_in[7];
    const float* bhh   = (const float*)d_in[8];
    float* out = (float*)d_out;
    const int N = in_sizes[0] / 3;

    // ws (shorts): wh 327680 | whh 81920 | gf_hi 20480 | gf_lo 20480  (0.90 MB)
    short* wh    = (short*)d_ws;
    short* whh   = wh + 327680;
    short* gf_hi = whh + 81920;
    short* gf_lo = gf_hi + 20480;

    ffb_pack<<<210, 256, 0, stream>>>(Wh, Whh, ffnA, wh, whh, gf_hi, gf_lo);
    ffb_main<<<N / TM, 256, 0, stream>>>(pos, gfeat, W0, b0, bh, bhh,
                                         wh, whh, gf_hi, gf_lo, out);
}

// Round 9
// 230.371 us; speedup vs baseline: 3.3493x; 1.0820x over previous
//
#include <hip/hip_runtime.h>

// FFB encoder fused kernel, MI355X (gfx950). Round 9.
//  vs round 8: occupancy play — 4 blocks/CU.
//   - Grid branch hi-only: g and ffnA single f16 planes (error budget:
//     adds ~5e-3 absmax; measured headroom 0.0625 -> 0.1). gf B-frags
//     pre-scaled by 2^(l-1) (exact) because both A k-halves now carry g_hi,
//     doubling the k-sum.
//   - LDS 47.1 KB -> 40,960 B exactly (s_x 33792 + s_g 6144 + pos 768)
//     -> 4 blocks/CU = 16 waves/CU (was 3/12). Better phase-offset overlap
//     of MFMA vs VALU(sin) vs barrier drain across blocks.
//   - Live-set trim: g lo-frags gone (-16 VGPR), one ga per m-tile.
//     Also probes the R8 WRITE_SIZE anomaly (+23 MB suspected spills).
//  Kept from R8: TM=64, 64x64 GEMM1 tiles w/ 2-deep B ring, head 4 m-tiles,
//  f16 single-product GEMMs, stride-264 LDS, reg-dbuf head B.

#define TM 64
#define XSTRIDE 264
#define GSTRIDE 48
#define K5 0.79577471545947667f         // 5/(2*pi)

typedef __attribute__((ext_vector_type(8))) _Float16 v8h;
typedef __attribute__((ext_vector_type(2))) __fp16 hw2;
typedef __attribute__((ext_vector_type(4))) float v4f;
typedef __attribute__((ext_vector_type(16))) float v16f;

#define MFMA16H(a, b, c) __builtin_amdgcn_mfma_f32_16x16x32_f16(a, b, c, 0, 0, 0)
#define MFMA32H(a, b, c) __builtin_amdgcn_mfma_f32_32x32x16_f16(a, b, c, 0, 0, 0)

__device__ __forceinline__ float sin_rev(float u) {
#if __has_builtin(__builtin_amdgcn_fractf)
    return __builtin_amdgcn_sinf(__builtin_amdgcn_fractf(u));
#else
    return __builtin_amdgcn_sinf(u - floorf(u));
#endif
}

__device__ __forceinline__ short f16s(float x) {      // RNE f32->f16
    _Float16 hh = (_Float16)x;
    return __builtin_bit_cast(short, hh);
}

// ---------------- weight packing ----------------
// wh  f16: [l][kb16][nt8][lane64][8]  (327680 shorts), scaled by K5
// whh f16: [l][kb8][nt4][lane64][8]   (81920 shorts),  scaled by K5
// gf  f16: [l][nt8][lane64][8]        (20480 shorts),  ffnA*2^(l-1)
//          (k-halves duplicated; A carries g_hi in both halves -> sum doubles)
__global__ __launch_bounds__(256) void ffb_pack(
    const float* __restrict__ Wh, const float* __restrict__ Whh,
    const float* __restrict__ ffnA,
    short* __restrict__ wh, short* __restrict__ whh, short* __restrict__ gf)
{
    int t = blockIdx.x * 256 + threadIdx.x;
    if (t < 40960) {                       // (l, kb, nt, lane)
        int lane = t & 63, nt = (t >> 6) & 7, kb = (t >> 9) & 15, l = t >> 13;
        int n = nt * 32 + (lane & 31);
        int k0 = kb * 16 + (lane >> 5) * 8;
        short hs[8];
        #pragma unroll
        for (int jj = 0; jj < 8; jj++)
            hs[jj] = f16s(Wh[(l * 256 + k0 + jj) * 256 + n] * K5);
        *(v8h*)(wh + t * 8) = *(v8h*)hs;
    } else if (t < 51200) {
        int t2 = t - 40960;                // (l, kb, nt, lane)
        int lane = t2 & 63, nt = (t2 >> 6) & 3, kb = (t2 >> 8) & 7, l = t2 >> 11;
        int n = nt * 16 + (lane & 15);
        int k0 = kb * 32 + (lane >> 4) * 8;
        short hs[8];
        #pragma unroll
        for (int jj = 0; jj < 8; jj++)
            hs[jj] = f16s(Whh[(l * 256 + k0 + jj) * 64 + n] * K5);
        *(v8h*)(whh + t2 * 8) = *(v8h*)hs;
    } else if (t < 53760) {
        int t3 = t - 51200;                // (l, nt, lane)
        int lane = t3 & 63, nt = (t3 >> 6) & 7, l = t3 >> 9;
        int n = nt * 32 + (lane & 31);
        const float sc = 0.5f * (float)(1 << l);       // 2^(l-1), exact
        short hs[8];
        #pragma unroll
        for (int jj = 0; jj < 8; jj++)
            hs[jj] = f16s(ffnA[(l * 8 + jj) * 256 + n] * sc);
        *(v8h*)(gf + t3 * 8) = *(v8h*)hs;
    }
}

// ---------------- main fused kernel ----------------
__global__ __launch_bounds__(256, 3) void ffb_main(
    const float* __restrict__ pos, const float* __restrict__ gfeat,
    const float* __restrict__ W0, const float* __restrict__ b0,
    const float* __restrict__ bh, const float* __restrict__ bhh,
    const short* __restrict__ wh, const short* __restrict__ whh,
    const short* __restrict__ gf,
    float* __restrict__ out)
{
    __shared__ __align__(16) short s_x[TM * XSTRIDE];   // f16  (33792 B)
    __shared__ __align__(16) short s_g[TM * GSTRIDE];   // f16  (6144 B)
    __shared__ float s_pos[TM * 3];                     //      (768 B)

    const int tid = threadIdx.x;
    const int row0 = blockIdx.x * TM;
    const int lane = tid & 63;
    const int w = tid >> 6;
    const int i = lane & 15;
    const int q = lane >> 4;
    const int m32 = lane & 31;
    const int h = lane >> 5;

    if (tid < TM * 3) s_pos[tid] = pos[row0 * 3 + tid];
    for (int k2 = tid; k2 < TM * 40; k2 += 256) {
        int r = k2 / 40, f = k2 % 40;
        s_g[r * GSTRIDE + f] = f16s(gfeat[row0 * 40 + k2]);
    }
    __syncthreads();

    // layer 0: x = sin(5*(pos@W0 + b0))
    {
        const int c = tid;
        const float w00 = W0[c], w01 = W0[256 + c], w02 = W0[512 + c], bc = b0[c];
        #pragma unroll 4
        for (int r = 0; r < TM; r++) {
            float d = s_pos[r * 3 + 0] * w00 + s_pos[r * 3 + 1] * w01
                    + s_pos[r * 3 + 2] * w02 + bc;
            s_x[r * XSTRIDE + c] = f16s(sin_rev(d * K5));
        }
    }
    __syncthreads();

    float cout[4][4];
    #pragma unroll
    for (int m = 0; m < 4; m++)
        #pragma unroll
        for (int r = 0; r < 4; r++) cout[m][r] = 0.f;

    const int a1off0 = m32 * XSTRIDE + h * 8;            // m-tile 0, + kb*16
    const int a1off1 = (32 + m32) * XSTRIDE + h * 8;     // m-tile 1

    for (int l = 0; l < 5; l++) {
        // ---- bias-init C1 (pre-scaled by K5), prefetch G B-frags ----
        const float bias0 = bh[l * 256 + w * 64 + m32] * K5;
        const float bias1 = bh[l * 256 + w * 64 + 32 + m32] * K5;
        v16f C1[2][2];
        #pragma unroll
        for (int r = 0; r < 16; r++) {
            C1[0][0][r] = bias0; C1[1][0][r] = bias0;
            C1[0][1][r] = bias1; C1[1][1][r] = bias1;
        }
        v8h gb0 = *(const v8h*)(gf + ((l * 8 + w * 2 + 0) * 64 + lane) * 8);
        v8h gb1 = *(const v8h*)(gf + ((l * 8 + w * 2 + 1) * 64 + lane) * 8);

        // ---- GEMM1: 64 rows x 64 cols per wave, 2-deep B prefetch ----
        {
            const short* bp = wh + l * 65536 + (2 * w) * 512 + lane * 8;
            v8h rb0[3], rb1[3];
            rb0[0] = *(const v8h*)(bp);
            rb1[0] = *(const v8h*)(bp + 512);
            rb0[1] = *(const v8h*)(bp + 4096);
            rb1[1] = *(const v8h*)(bp + 4096 + 512);
            #pragma unroll
            for (int kb = 0; kb < 16; kb++) {
                if (kb + 2 < 16) {
                    rb0[(kb + 2) % 3] = *(const v8h*)(bp + (kb + 2) * 4096);
                    rb1[(kb + 2) % 3] = *(const v8h*)(bp + (kb + 2) * 4096 + 512);
                }
                v8h a0 = *(const v8h*)&s_x[a1off0 + kb * 16];
                v8h a1 = *(const v8h*)&s_x[a1off1 + kb * 16];
                v8h bc0 = rb0[kb % 3], bc1 = rb1[kb % 3];
                C1[0][0] = MFMA32H(a0, bc0, C1[0][0]);
                C1[0][1] = MFMA32H(a0, bc1, C1[0][1]);
                C1[1][0] = MFMA32H(a1, bc0, C1[1][0]);
                C1[1][1] = MFMA32H(a1, bc1, C1[1][1]);
            }
        }
        __syncthreads();   // all waves done reading x_l

        // ---- epilogue: x = sin(C1) + sin(G), G = g@(ffnA*2^l) ----
        // A-frag: both k-halves carry g_hi (same LDS addr for lane and
        // lane+32 -> broadcast); gf pre-scaled by 2^(l-1) so sum lands 2^l.
        #pragma unroll
        for (int m = 0; m < 2; m++) {
            v8h ga = *(const v8h*)&s_g[(m * 32 + m32) * GSTRIDE + l * 8];
            #pragma unroll
            for (int t = 0; t < 2; t++) {
                v16f Z = {};
                v16f G = MFMA32H(ga, (t ? gb1 : gb0), Z);
                const int col = w * 64 + t * 32 + m32;
                #pragma unroll
                for (int r = 0; r < 16; r++) {
                    const int row = m * 32 + (r & 3) + 8 * (r >> 2) + 4 * h;
                    float v = sin_rev(C1[m][t][r]) + sin_rev(G[r]);
                    s_x[row * XSTRIDE + col] = f16s(v);
                }
            }
        }
        __syncthreads();   // new x visible

        // ---- GEMM2: head, 64 rows x 16 cols per wave (4 m-tiles) ----
        const float b2 = bhh[l * 64 + w * 16 + i] * K5;
        v4f C2[4];
        #pragma unroll
        for (int m = 0; m < 4; m++) C2[m] = (v4f){b2, b2, b2, b2};
        {
            const short* bp = whh + l * 16384 + w * 512 + lane * 8;
            v8h bc = *(const v8h*)(bp);
            #pragma unroll
            for (int kb = 0; kb < 8; kb++) {
                const int kn = (kb < 7) ? (kb + 1) : 7;
                v8h bn = *(const v8h*)(bp + kn * 2048);
                #pragma unroll
                for (int m = 0; m < 4; m++) {
                    v8h a = *(const v8h*)&s_x[(m * 16 + i) * XSTRIDE + q * 8 + kb * 32];
                    C2[m] = MFMA16H(a, bc, C2[m]);
                }
                bc = bn;
            }
        }
        #pragma unroll
        for (int m = 0; m < 4; m++)
            #pragma unroll
            for (int r = 0; r < 4; r++)
                cout[m][r] += sin_rev(C2[m][r]);
        // no barrier: next GEMM1 reads same x; overwrites after its own barrier
    }

    // ---- store x_out ----
    #pragma unroll
    for (int m = 0; m < 4; m++)
        #pragma unroll
        for (int r = 0; r < 4; r++)
            out[(row0 + m * 16 + q * 4 + r) * 64 + w * 16 + i] = cout[m][r];
}

extern "C" void kernel_launch(void* const* d_in, const int* in_sizes, int n_in,
                              void* d_out, int out_size, void* d_ws, size_t ws_size,
                              hipStream_t stream) {
    const float* pos   = (const float*)d_in[0];
    const float* gfeat = (const float*)d_in[1];
    const float* ffnA  = (const float*)d_in[2];
    const float* W0    = (const float*)d_in[3];
    const float* b0    = (const float*)d_in[4];
    const float* Wh    = (const float*)d_in[5];
    const float* bh    = (const float*)d_in[6];
    const float* Whh   = (const float*)d_in[7];
    const float* bhh   = (const float*)d_in[8];
    float* out = (float*)d_out;
    const int N = in_sizes[0] / 3;

    // ws (shorts): wh 327680 | whh 81920 | gf 20480   (0.86 MB)
    short* wh  = (short*)d_ws;
    short* whh = wh + 327680;
    short* gf  = whh + 81920;

    ffb_pack<<<210, 256, 0, stream>>>(Wh, Whh, ffnA, wh, whh, gf);
    ffb_main<<<N / TM, 256, 0, stream>>>(pos, gfeat, W0, b0, bh, bhh,
                                         wh, whh, gf, out);
}